// Round 1
// baseline (503.654 us; speedup 1.0000x reference)
//
#include <hip/hip_runtime.h>
#include <hip/hip_bf16.h>
#include <stdint.h>

#define DEV __device__ __forceinline__

typedef __attribute__((ext_vector_type(8))) short     short8;   // 8 x bf16 bits
typedef __attribute__((ext_vector_type(4))) float     f32x4;
typedef __attribute__((ext_vector_type(4))) unsigned short ushort4v;

DEV float bf2f(unsigned short u) { return __uint_as_float(((uint32_t)u) << 16); }
DEV unsigned short f2bf(float f) {
    uint32_t x = __float_as_uint(f);
    return (unsigned short)((x + 0x7FFFu + ((x >> 16) & 1u)) >> 16);  // RNE
}

DEV f32x4 mfma16(short8 a, short8 b, f32x4 c) {
    return __builtin_amdgcn_mfma_f32_16x16x32_bf16(a, b, c, 0, 0, 0);
}

#define AS1C const __attribute__((address_space(1)))
#define AS3  __attribute__((address_space(3)))

DEV void gload_lds16(const void* g, void* l) {
    __builtin_amdgcn_global_load_lds((AS1C void*)g, (AS3 void*)l, 16, 0, 0);
}

// ---------------------------------------------------------------- LayerNorm
// one wave per 768-float row, writes bf16
__global__ __launch_bounds__(256) void ln_kernel(const float* __restrict__ x,
                                                 const float* __restrict__ g,
                                                 const float* __restrict__ b,
                                                 unsigned short* __restrict__ out)
{
    const int lane = threadIdx.x & 63;
    const int row  = blockIdx.x * 4 + (threadIdx.x >> 6);
    const float* xr = x + (size_t)row * 768;

    f32x4 v[3];
    float s = 0.f, sq = 0.f;
#pragma unroll
    for (int i = 0; i < 3; ++i) {
        v[i] = *(const f32x4*)(xr + i * 256 + lane * 4);
#pragma unroll
        for (int j = 0; j < 4; ++j) { s += v[i][j]; sq = fmaf(v[i][j], v[i][j], sq); }
    }
#pragma unroll
    for (int off = 32; off; off >>= 1) { s += __shfl_xor(s, off); sq += __shfl_xor(sq, off); }
    const float mean = s * (1.0f / 768.0f);
    const float rstd = rsqrtf(sq * (1.0f / 768.0f) - mean * mean + 1e-5f);

#pragma unroll
    for (int i = 0; i < 3; ++i) {
        f32x4 gg = *(const f32x4*)(g + i * 256 + lane * 4);
        f32x4 bb = *(const f32x4*)(b + i * 256 + lane * 4);
        ushort4v o;
#pragma unroll
        for (int j = 0; j < 4; ++j) o[j] = f2bf((v[i][j] - mean) * rstd * gg[j] + bb[j]);
        *(ushort4v*)(out + (size_t)row * 768 + i * 256 + lane * 4) = o;
    }
}

// ------------------------------------------- weight convert fp32[K][N] -> bf16[N][K]
__global__ __launch_bounds__(256) void wconv_kernel(const float* __restrict__ W,
                                                    unsigned short* __restrict__ Wt,
                                                    int K, int N)
{
    __shared__ float t[32][33];
    const int tx = threadIdx.x & 31, ty = threadIdx.x >> 5;
    const int n0 = blockIdx.x * 32, k0 = blockIdx.y * 32;
#pragma unroll
    for (int i = 0; i < 4; ++i)
        t[ty + i * 8][tx] = W[(size_t)(k0 + ty + i * 8) * N + n0 + tx];
    __syncthreads();
#pragma unroll
    for (int i = 0; i < 4; ++i)
        Wt[(size_t)(n0 + ty + i * 8) * K + k0 + tx] = f2bf(t[tx][ty + i * 8]);
}

// ---------------------------------------------------------------- GEMM (NT)
// C[M][N] = A[M][K](bf16) * Bt[N][K](bf16)^T, 128x128 tile, BK=32, 4 waves.
// EPI 0: out = bf16(acc + bias)
// EPI 1: out = f32 (acc + bias + res)
// EPI 2: out = bf16(gelu_exact(acc + bias))
template <int EPI>
__global__ __launch_bounds__(256) void gemm_bt(const unsigned short* __restrict__ A,
                                               const unsigned short* __restrict__ Bt,
                                               const float* __restrict__ bias,
                                               const float* __restrict__ res,
                                               float* __restrict__ outf,
                                               unsigned short* __restrict__ outh,
                                               int M, int N, int K)
{
    __shared__ unsigned short As[128 * 32];
    __shared__ unsigned short Bs[128 * 32];
    const int tid = threadIdx.x;
    const int lane = tid & 63, wv = tid >> 6;
    const int r16 = lane & 15, g4 = lane >> 4;
    const int wm = wv >> 1, wn = wv & 1;
    const int n0 = blockIdx.x * 128, m0 = blockIdx.y * 128;

    f32x4 acc[4][4] = {};

    for (int k0 = 0; k0 < K; k0 += 32) {
#pragma unroll
        for (int i = 0; i < 2; ++i) {
            const int chunk0 = wv * 128 + i * 64;           // wave-uniform LDS base
            const int c = chunk0 + lane;                     // 16B chunk id
            const unsigned short* ga = A  + (size_t)(m0 + (c >> 2)) * K + k0 + (c & 3) * 8;
            const unsigned short* gb = Bt + (size_t)(n0 + (c >> 2)) * K + k0 + (c & 3) * 8;
            gload_lds16(ga, (char*)As + (size_t)chunk0 * 16);
            gload_lds16(gb, (char*)Bs + (size_t)chunk0 * 16);
        }
        __syncthreads();

        short8 af[4], bfr[4];
#pragma unroll
        for (int i = 0; i < 4; ++i)
            af[i] = *(const short8*)(As + (wm * 64 + i * 16 + r16) * 32 + g4 * 8);
#pragma unroll
        for (int j = 0; j < 4; ++j)
            bfr[j] = *(const short8*)(Bs + (wn * 64 + j * 16 + r16) * 32 + g4 * 8);
#pragma unroll
        for (int i = 0; i < 4; ++i)
#pragma unroll
            for (int j = 0; j < 4; ++j)
                acc[i][j] = mfma16(af[i], bfr[j], acc[i][j]);
        __syncthreads();
    }

#pragma unroll
    for (int i = 0; i < 4; ++i) {
#pragma unroll
        for (int j = 0; j < 4; ++j) {
            const int row = m0 + wm * 64 + i * 16 + g4 * 4;
            const int col = n0 + wn * 64 + j * 16 + r16;
            const float bv = bias[col];
#pragma unroll
            for (int r = 0; r < 4; ++r) {
                const float v = acc[i][j][r] + bv;
                const size_t idx = (size_t)(row + r) * N + col;
                if constexpr (EPI == 0) {
                    outh[idx] = f2bf(v);
                } else if constexpr (EPI == 1) {
                    outf[idx] = v + res[idx];
                } else {
                    const float ge = 0.5f * v * (1.0f + erff(v * 0.70710678118654752f));
                    outh[idx] = f2bf(ge);
                }
            }
        }
    }
}

// ---------------------------------------------------------------- attention
// 1 wave per block, 32 q-rows per block, causal flash over 32-key steps.
__global__ __launch_bounds__(64) void attn_kernel(const unsigned short* __restrict__ qkv,
                                                  unsigned short* __restrict__ out)
{
    __shared__ unsigned short P_lds[2][16][40];   // padded: 80B row stride, 16B aligned
    const int l = threadIdx.x;
    const int r16 = l & 15, g4 = l >> 4;
    const int bx = blockIdx.x;
    const int qt = bx & 31;
    const int h  = (bx >> 5) % 12;
    const int b  = bx / (32 * 12);
    const int C3 = 2304, T = 1024;
    const int gr0 = b * T + qt * 32;
    const int qc  = h * 64;

    short8 qf[2][2];   // pre-scaled by 1/8 (exact in bf16)
#pragma unroll
    for (int mt = 0; mt < 2; ++mt)
#pragma unroll
        for (int ks = 0; ks < 2; ++ks) {
            short8 v = *(const short8*)(qkv + (size_t)(gr0 + mt * 16 + r16) * C3 + qc + ks * 32 + g4 * 8);
#pragma unroll
            for (int j = 0; j < 8; ++j)
                v[j] = (short)f2bf(bf2f((unsigned short)v[j]) * 0.125f);
            qf[mt][ks] = v;
        }

    f32x4 o[2][4] = {};
    float mst[2][4], lst[2][4];
#pragma unroll
    for (int mt = 0; mt < 2; ++mt)
#pragma unroll
        for (int r = 0; r < 4; ++r) { mst[mt][r] = -1e30f; lst[mt][r] = 0.f; }

    const int nst = qt + 1;
    for (int s = 0; s < nst; ++s) {
        const int k0 = s * 32;
        const unsigned short* kb = qkv + (size_t)(b * T + k0) * C3 + 768 + qc;
        short8 kf[2][2];
#pragma unroll
        for (int kt = 0; kt < 2; ++kt)
#pragma unroll
            for (int ks = 0; ks < 2; ++ks)
                kf[kt][ks] = *(const short8*)(kb + (size_t)(kt * 16 + r16) * C3 + ks * 32 + g4 * 8);

        f32x4 sv[2][2] = {};
#pragma unroll
        for (int mt = 0; mt < 2; ++mt)
#pragma unroll
            for (int kt = 0; kt < 2; ++kt)
#pragma unroll
                for (int ks = 0; ks < 2; ++ks)
                    sv[mt][kt] = mfma16(qf[mt][ks], kf[kt][ks], sv[mt][kt]);

        if (s == qt) {   // diagonal tile: causal mask
#pragma unroll
            for (int mt = 0; mt < 2; ++mt)
#pragma unroll
                for (int kt = 0; kt < 2; ++kt)
#pragma unroll
                    for (int r = 0; r < 4; ++r)
                        if (k0 + kt * 16 + r16 > qt * 32 + mt * 16 + g4 * 4 + r)
                            sv[mt][kt][r] = -1e30f;
        }

        __syncthreads();   // previous iteration's P reads done before overwrite
#pragma unroll
        for (int mt = 0; mt < 2; ++mt) {
#pragma unroll
            for (int r = 0; r < 4; ++r) {
                float mx = fmaxf(sv[mt][0][r], sv[mt][1][r]);
#pragma unroll
                for (int off = 8; off; off >>= 1) mx = fmaxf(mx, __shfl_xor(mx, off));
                const float mnew  = fmaxf(mst[mt][r], mx);
                const float alpha = __expf(mst[mt][r] - mnew);
                mst[mt][r] = mnew;
                const float p0 = __expf(sv[mt][0][r] - mnew);
                const float p1 = __expf(sv[mt][1][r] - mnew);
                float rs = p0 + p1;
#pragma unroll
                for (int off = 8; off; off >>= 1) rs += __shfl_xor(rs, off);
                lst[mt][r] = lst[mt][r] * alpha + rs;
                P_lds[mt][g4 * 4 + r][r16]      = f2bf(p0);
                P_lds[mt][g4 * 4 + r][16 + r16] = f2bf(p1);
#pragma unroll
                for (int n = 0; n < 4; ++n) o[mt][n][r] *= alpha;
            }
        }
        __syncthreads();

        const unsigned short* vb = qkv + (size_t)(b * T + k0) * C3 + 1536 + qc;
        short8 vf[4];
#pragma unroll
        for (int n = 0; n < 4; ++n) {
            short8 t;
#pragma unroll
            for (int j = 0; j < 8; ++j)
                t[j] = (short)vb[(size_t)(g4 * 8 + j) * C3 + n * 16 + r16];
            vf[n] = t;
        }
        short8 pa[2];
        pa[0] = *(const short8*)&P_lds[0][r16][g4 * 8];
        pa[1] = *(const short8*)&P_lds[1][r16][g4 * 8];
#pragma unroll
        for (int mt = 0; mt < 2; ++mt)
#pragma unroll
            for (int n = 0; n < 4; ++n)
                o[mt][n] = mfma16(pa[mt], vf[n], o[mt][n]);
    }

#pragma unroll
    for (int mt = 0; mt < 2; ++mt)
#pragma unroll
        for (int n = 0; n < 4; ++n)
#pragma unroll
            for (int r = 0; r < 4; ++r)
                out[(size_t)(gr0 + mt * 16 + g4 * 4 + r) * 768 + qc + n * 16 + r16] =
                    f2bf(o[mt][n][r] / lst[mt][r]);
}

// ---------------------------------------------------------------- launcher
extern "C" void kernel_launch(void* const* d_in, const int* in_sizes, int n_in,
                              void* d_out, int out_size, void* d_ws, size_t ws_size,
                              hipStream_t stream)
{
    const float* x     = (const float*)d_in[0];
    const float* ln1g  = (const float*)d_in[1];
    const float* ln1b  = (const float*)d_in[2];
    const float* Wattn = (const float*)d_in[3];
    const float* battn = (const float*)d_in[4];
    const float* Wproj = (const float*)d_in[5];
    const float* bproj = (const float*)d_in[6];
    const float* ln2g  = (const float*)d_in[7];
    const float* ln2b  = (const float*)d_in[8];
    const float* Wfc   = (const float*)d_in[9];
    const float* bfc   = (const float*)d_in[10];
    const float* Wfc2  = (const float*)d_in[11];
    const float* bfc2  = (const float*)d_in[12];
    float* out = (float*)d_out;

    char* p = (char*)d_ws;
    auto alloc = [&](size_t bytes) { char* q = p; p += (bytes + 255) & ~(size_t)255; return q; };
    unsigned short* wt_attn = (unsigned short*)alloc(768ull * 2304 * 2);
    unsigned short* wt_proj = (unsigned short*)alloc(768ull * 768 * 2);
    unsigned short* wt_fc   = (unsigned short*)alloc(768ull * 3072 * 2);
    unsigned short* wt_fc2  = (unsigned short*)alloc(3072ull * 768 * 2);
    unsigned short* bufA    = (unsigned short*)alloc(8192ull * 768 * 2);   // xln1 -> attn_out -> hln2
    unsigned short* bufB    = (unsigned short*)alloc(8192ull * 3072 * 2);  // qkv -> h_act
    float*          x1      = (float*)alloc(8192ull * 768 * 4);            // x + attn residual

    const int M = 8192;

    wconv_kernel<<<dim3(2304 / 32, 768 / 32), 256, 0, stream>>>(Wattn, wt_attn, 768, 2304);
    wconv_kernel<<<dim3(768 / 32, 768 / 32), 256, 0, stream>>>(Wproj, wt_proj, 768, 768);
    wconv_kernel<<<dim3(3072 / 32, 768 / 32), 256, 0, stream>>>(Wfc, wt_fc, 768, 3072);
    wconv_kernel<<<dim3(768 / 32, 3072 / 32), 256, 0, stream>>>(Wfc2, wt_fc2, 3072, 768);

    ln_kernel<<<2048, 256, 0, stream>>>(x, ln1g, ln1b, bufA);

    gemm_bt<0><<<dim3(2304 / 128, M / 128), 256, 0, stream>>>(
        bufA, wt_attn, battn, (const float*)nullptr, (float*)nullptr, bufB, M, 2304, 768);

    attn_kernel<<<dim3(8 * 12 * 32), 64, 0, stream>>>(bufB, bufA);

    gemm_bt<1><<<dim3(768 / 128, M / 128), 256, 0, stream>>>(
        bufA, wt_proj, bproj, x, x1, (unsigned short*)nullptr, M, 768, 768);

    ln_kernel<<<2048, 256, 0, stream>>>(x1, ln2g, ln2b, bufA);

    gemm_bt<2><<<dim3(3072 / 128, M / 128), 256, 0, stream>>>(
        bufA, wt_fc, bfc, (const float*)nullptr, (float*)nullptr, bufB, M, 3072, 768);

    gemm_bt<1><<<dim3(768 / 128, M / 128), 256, 0, stream>>>(
        bufB, wt_fc2, bfc2, x1, out, (unsigned short*)nullptr, M, 768, 3072);
}

// Round 2
// 490.926 us; speedup vs baseline: 1.0259x; 1.0259x over previous
//
#include <hip/hip_runtime.h>
#include <hip/hip_bf16.h>
#include <stdint.h>

#define DEV __device__ __forceinline__

typedef __attribute__((ext_vector_type(8))) short     short8;   // 8 x bf16 bits
typedef __attribute__((ext_vector_type(4))) float     f32x4;
typedef __attribute__((ext_vector_type(4))) unsigned short ushort4v;

DEV float bf2f(unsigned short u) { return __uint_as_float(((uint32_t)u) << 16); }
DEV unsigned short f2bf(float f) {
    uint32_t x = __float_as_uint(f);
    return (unsigned short)((x + 0x7FFFu + ((x >> 16) & 1u)) >> 16);  // RNE
}

DEV f32x4 mfma16(short8 a, short8 b, f32x4 c) {
    return __builtin_amdgcn_mfma_f32_16x16x32_bf16(a, b, c, 0, 0, 0);
}

#define AS1C const __attribute__((address_space(1)))
#define AS3  __attribute__((address_space(3)))

DEV void gload_lds16(const void* g, void* l) {
    __builtin_amdgcn_global_load_lds((AS1C void*)g, (AS3 void*)l, 16, 0, 0);
}

// ---------------------------------------------------------------- LayerNorm
__global__ __launch_bounds__(256) void ln_kernel(const float* __restrict__ x,
                                                 const float* __restrict__ g,
                                                 const float* __restrict__ b,
                                                 unsigned short* __restrict__ out)
{
    const int lane = threadIdx.x & 63;
    const int row  = blockIdx.x * 4 + (threadIdx.x >> 6);
    const float* xr = x + (size_t)row * 768;

    f32x4 v[3];
    float s = 0.f, sq = 0.f;
#pragma unroll
    for (int i = 0; i < 3; ++i) {
        v[i] = *(const f32x4*)(xr + i * 256 + lane * 4);
#pragma unroll
        for (int j = 0; j < 4; ++j) { s += v[i][j]; sq = fmaf(v[i][j], v[i][j], sq); }
    }
#pragma unroll
    for (int off = 32; off; off >>= 1) { s += __shfl_xor(s, off); sq += __shfl_xor(sq, off); }
    const float mean = s * (1.0f / 768.0f);
    const float rstd = rsqrtf(sq * (1.0f / 768.0f) - mean * mean + 1e-5f);

#pragma unroll
    for (int i = 0; i < 3; ++i) {
        f32x4 gg = *(const f32x4*)(g + i * 256 + lane * 4);
        f32x4 bb = *(const f32x4*)(b + i * 256 + lane * 4);
        ushort4v o;
#pragma unroll
        for (int j = 0; j < 4; ++j) o[j] = f2bf((v[i][j] - mean) * rstd * gg[j] + bb[j]);
        *(ushort4v*)(out + (size_t)row * 768 + i * 256 + lane * 4) = o;
    }
}

// ------------------------------------------- weight convert fp32[K][N] -> bf16[N][K]
__global__ __launch_bounds__(256) void wconv_kernel(const float* __restrict__ W,
                                                    unsigned short* __restrict__ Wt,
                                                    int K, int N)
{
    __shared__ float t[32][33];
    const int tx = threadIdx.x & 31, ty = threadIdx.x >> 5;
    const int n0 = blockIdx.x * 32, k0 = blockIdx.y * 32;
#pragma unroll
    for (int i = 0; i < 4; ++i)
        t[ty + i * 8][tx] = W[(size_t)(k0 + ty + i * 8) * N + n0 + tx];
    __syncthreads();
#pragma unroll
    for (int i = 0; i < 4; ++i)
        Wt[(size_t)(n0 + ty + i * 8) * K + k0 + tx] = f2bf(t[tx][ty + i * 8]);
}

// ---------------------------------------------------------------- GEMM (NT)
template <int EPI>
__global__ __launch_bounds__(256) void gemm_bt(const unsigned short* __restrict__ A,
                                               const unsigned short* __restrict__ Bt,
                                               const float* __restrict__ bias,
                                               const float* __restrict__ res,
                                               float* __restrict__ outf,
                                               unsigned short* __restrict__ outh,
                                               int M, int N, int K)
{
    __shared__ unsigned short As[128 * 32];
    __shared__ unsigned short Bs[128 * 32];
    const int tid = threadIdx.x;
    const int lane = tid & 63, wv = tid >> 6;
    const int r16 = lane & 15, g4 = lane >> 4;
    const int wm = wv >> 1, wn = wv & 1;
    const int n0 = blockIdx.x * 128, m0 = blockIdx.y * 128;

    f32x4 acc[4][4] = {};

    for (int k0 = 0; k0 < K; k0 += 32) {
#pragma unroll
        for (int i = 0; i < 2; ++i) {
            const int chunk0 = wv * 128 + i * 64;           // wave-uniform LDS base
            const int c = chunk0 + lane;                     // 16B chunk id
            const unsigned short* ga = A  + (size_t)(m0 + (c >> 2)) * K + k0 + (c & 3) * 8;
            const unsigned short* gb = Bt + (size_t)(n0 + (c >> 2)) * K + k0 + (c & 3) * 8;
            gload_lds16(ga, (char*)As + (size_t)chunk0 * 16);
            gload_lds16(gb, (char*)Bs + (size_t)chunk0 * 16);
        }
        __syncthreads();

        short8 af[4], bfr[4];
#pragma unroll
        for (int i = 0; i < 4; ++i)
            af[i] = *(const short8*)(As + (wm * 64 + i * 16 + r16) * 32 + g4 * 8);
#pragma unroll
        for (int j = 0; j < 4; ++j)
            bfr[j] = *(const short8*)(Bs + (wn * 64 + j * 16 + r16) * 32 + g4 * 8);
#pragma unroll
        for (int i = 0; i < 4; ++i)
#pragma unroll
            for (int j = 0; j < 4; ++j)
                acc[i][j] = mfma16(af[i], bfr[j], acc[i][j]);
        __syncthreads();
    }

#pragma unroll
    for (int i = 0; i < 4; ++i) {
#pragma unroll
        for (int j = 0; j < 4; ++j) {
            const int row = m0 + wm * 64 + i * 16 + g4 * 4;
            const int col = n0 + wn * 64 + j * 16 + r16;
            const float bv = bias[col];
#pragma unroll
            for (int r = 0; r < 4; ++r) {
                const float v = acc[i][j][r] + bv;
                const size_t idx = (size_t)(row + r) * N + col;
                if constexpr (EPI == 0) {
                    outh[idx] = f2bf(v);
                } else if constexpr (EPI == 1) {
                    outf[idx] = v + res[idx];
                } else {
                    const float ge = 0.5f * v * (1.0f + erff(v * 0.70710678118654752f));
                    outh[idx] = f2bf(ge);
                }
            }
        }
    }
}

// ---------------------------------------------------------------- attention
// 4 waves/block, each wave owns 32 q-rows; block covers 128 q-rows.
// K/V tiles (32 keys x 64 dims) shared via LDS; K double-buffered via
// global_load_lds with XOR-swizzled source; V transposed via reg staging.
__global__ __launch_bounds__(256) void attn_kernel(const unsigned short* __restrict__ qkv,
                                                   unsigned short* __restrict__ out)
{
    __shared__ unsigned short K_lds[2][32][64];   // chunk-swizzled: phys chunk = c ^ (row&7)
    __shared__ unsigned short Vt[64][32];         // V transposed: Vt[d][k]
    __shared__ unsigned short P_lds[4][2][16][40];

    const int tid  = threadIdx.x;
    const int lane = tid & 63, wv = tid >> 6;
    const int r16 = lane & 15, g4 = lane >> 4;
    const int qb = blockIdx.x;            // 0..7 (128 q-rows each)
    const int h  = blockIdx.y;            // 0..11
    const int b  = blockIdx.z;            // 0..7
    const int C3 = 2304, T = 1024;
    const int qt  = qb * 4 + wv;          // this wave's global q-tile (32 rows)
    const int gr0 = b * T + qt * 32;
    const int qc  = h * 64;
    const int ns  = qb * 4 + 4;           // key steps for this block

    // staging roles: thread -> (row kr, 16B chunk kc8) of the 32x64 tile
    const int kr  = tid >> 3;             // 0..31
    const int kc8 = tid & 7;              // 0..7
    const unsigned short* kbase = qkv + (size_t)(b * T) * C3 + 768 + qc;
    const unsigned short* vbase = kbase + 768;

    // Q fragments, pre-scaled by 1/8 (exact in bf16)
    short8 qf[2][2];
#pragma unroll
    for (int mt = 0; mt < 2; ++mt)
#pragma unroll
        for (int ks = 0; ks < 2; ++ks) {
            short8 v = *(const short8*)(qkv + (size_t)(gr0 + mt * 16 + r16) * C3 + qc + ks * 32 + g4 * 8);
#pragma unroll
            for (int j = 0; j < 8; ++j)
                v[j] = (short)f2bf(bf2f((unsigned short)v[j]) * 0.125f);
            qf[mt][ks] = v;
        }

    f32x4 o[2][4] = {};
    float mst[2][4], lst[2][4];
#pragma unroll
    for (int mt = 0; mt < 2; ++mt)
#pragma unroll
        for (int r = 0; r < 4; ++r) { mst[mt][r] = -1e30f; lst[mt][r] = 0.f; }

    // prologue: issue staging for step 0
    gload_lds16(kbase + (size_t)kr * C3 + (size_t)(kc8 ^ (kr & 7)) * 8,
                (char*)K_lds[0] + (tid >> 6) * 1024);
    short8 vreg = *(const short8*)(vbase + (size_t)kr * C3 + kc8 * 8);

    for (int s = 0; s < ns; ++s) {
        __syncthreads();   // (1) K(s) gload drained; vreg(s) ready; prev-step LDS readers done
        const unsigned short* kb_s = &K_lds[s & 1][0][0];
#pragma unroll
        for (int j = 0; j < 8; ++j)
            Vt[kc8 * 8 + j][kr] = (unsigned short)vreg[j];
        __syncthreads();   // (2) Vt written
        if (s + 1 < ns) {  // prefetch next step under compute
            const size_t roff = (size_t)((s + 1) * 32 + kr) * C3;
            gload_lds16(kbase + roff + (size_t)(kc8 ^ (kr & 7)) * 8,
                        (char*)K_lds[(s + 1) & 1] + (tid >> 6) * 1024);
            vreg = *(const short8*)(vbase + roff + kc8 * 8);
        }

        if (s <= qt) {
            short8 kf[2][2];
#pragma unroll
            for (int kt = 0; kt < 2; ++kt)
#pragma unroll
                for (int ks = 0; ks < 2; ++ks) {
                    const int row = kt * 16 + r16;
                    const int pc  = (ks * 4 + g4) ^ (row & 7);
                    kf[kt][ks] = *(const short8*)(kb_s + row * 64 + pc * 8);
                }

            f32x4 sv[2][2] = {};
#pragma unroll
            for (int mt = 0; mt < 2; ++mt)
#pragma unroll
                for (int kt = 0; kt < 2; ++kt)
#pragma unroll
                    for (int ks = 0; ks < 2; ++ks)
                        sv[mt][kt] = mfma16(qf[mt][ks], kf[kt][ks], sv[mt][kt]);

            if (s == qt) {   // diagonal tile: causal mask
                const int k0 = s * 32;
#pragma unroll
                for (int mt = 0; mt < 2; ++mt)
#pragma unroll
                    for (int kt = 0; kt < 2; ++kt)
#pragma unroll
                        for (int r = 0; r < 4; ++r)
                            if (k0 + kt * 16 + r16 > qt * 32 + mt * 16 + g4 * 4 + r)
                                sv[mt][kt][r] = -1e30f;
            }

#pragma unroll
            for (int mt = 0; mt < 2; ++mt) {
#pragma unroll
                for (int r = 0; r < 4; ++r) {
                    float mx = fmaxf(sv[mt][0][r], sv[mt][1][r]);
#pragma unroll
                    for (int off = 8; off; off >>= 1) mx = fmaxf(mx, __shfl_xor(mx, off));
                    const float mnew  = fmaxf(mst[mt][r], mx);
                    const float alpha = __expf(mst[mt][r] - mnew);
                    mst[mt][r] = mnew;
                    const float p0 = __expf(sv[mt][0][r] - mnew);
                    const float p1 = __expf(sv[mt][1][r] - mnew);
                    float rs = p0 + p1;
#pragma unroll
                    for (int off = 8; off; off >>= 1) rs += __shfl_xor(rs, off);
                    lst[mt][r] = lst[mt][r] * alpha + rs;
                    P_lds[wv][mt][g4 * 4 + r][r16]      = f2bf(p0);
                    P_lds[wv][mt][g4 * 4 + r][16 + r16] = f2bf(p1);
#pragma unroll
                    for (int n = 0; n < 4; ++n) o[mt][n][r] *= alpha;
                }
            }

            short8 vf[4];
#pragma unroll
            for (int n = 0; n < 4; ++n)
                vf[n] = *(const short8*)&Vt[n * 16 + r16][g4 * 8];
            short8 pa[2];
            pa[0] = *(const short8*)&P_lds[wv][0][r16][g4 * 8];
            pa[1] = *(const short8*)&P_lds[wv][1][r16][g4 * 8];
#pragma unroll
            for (int mt = 0; mt < 2; ++mt)
#pragma unroll
                for (int n = 0; n < 4; ++n)
                    o[mt][n] = mfma16(pa[mt], vf[n], o[mt][n]);
        }
    }

#pragma unroll
    for (int mt = 0; mt < 2; ++mt)
#pragma unroll
        for (int n = 0; n < 4; ++n)
#pragma unroll
            for (int r = 0; r < 4; ++r)
                out[(size_t)(gr0 + mt * 16 + g4 * 4 + r) * 768 + qc + n * 16 + r16] =
                    f2bf(o[mt][n][r] / lst[mt][r]);
}

// ---------------------------------------------------------------- launcher
extern "C" void kernel_launch(void* const* d_in, const int* in_sizes, int n_in,
                              void* d_out, int out_size, void* d_ws, size_t ws_size,
                              hipStream_t stream)
{
    const float* x     = (const float*)d_in[0];
    const float* ln1g  = (const float*)d_in[1];
    const float* ln1b  = (const float*)d_in[2];
    const float* Wattn = (const float*)d_in[3];
    const float* battn = (const float*)d_in[4];
    const float* Wproj = (const float*)d_in[5];
    const float* bproj = (const float*)d_in[6];
    const float* ln2g  = (const float*)d_in[7];
    const float* ln2b  = (const float*)d_in[8];
    const float* Wfc   = (const float*)d_in[9];
    const float* bfc   = (const float*)d_in[10];
    const float* Wfc2  = (const float*)d_in[11];
    const float* bfc2  = (const float*)d_in[12];
    float* out = (float*)d_out;

    char* p = (char*)d_ws;
    auto alloc = [&](size_t bytes) { char* q = p; p += (bytes + 255) & ~(size_t)255; return q; };
    unsigned short* wt_attn = (unsigned short*)alloc(768ull * 2304 * 2);
    unsigned short* wt_proj = (unsigned short*)alloc(768ull * 768 * 2);
    unsigned short* wt_fc   = (unsigned short*)alloc(768ull * 3072 * 2);
    unsigned short* wt_fc2  = (unsigned short*)alloc(3072ull * 768 * 2);
    unsigned short* bufA    = (unsigned short*)alloc(8192ull * 768 * 2);   // xln1 -> attn_out -> hln2
    unsigned short* bufB    = (unsigned short*)alloc(8192ull * 3072 * 2);  // qkv -> h_act
    float*          x1      = (float*)alloc(8192ull * 768 * 4);            // x + attn residual

    const int M = 8192;

    wconv_kernel<<<dim3(2304 / 32, 768 / 32), 256, 0, stream>>>(Wattn, wt_attn, 768, 2304);
    wconv_kernel<<<dim3(768 / 32, 768 / 32), 256, 0, stream>>>(Wproj, wt_proj, 768, 768);
    wconv_kernel<<<dim3(3072 / 32, 768 / 32), 256, 0, stream>>>(Wfc, wt_fc, 768, 3072);
    wconv_kernel<<<dim3(768 / 32, 3072 / 32), 256, 0, stream>>>(Wfc2, wt_fc2, 3072, 768);

    ln_kernel<<<2048, 256, 0, stream>>>(x, ln1g, ln1b, bufA);

    gemm_bt<0><<<dim3(2304 / 128, M / 128), 256, 0, stream>>>(
        bufA, wt_attn, battn, (const float*)nullptr, (float*)nullptr, bufB, M, 2304, 768);

    attn_kernel<<<dim3(8, 12, 8), 256, 0, stream>>>(bufB, bufA);

    gemm_bt<1><<<dim3(768 / 128, M / 128), 256, 0, stream>>>(
        bufA, wt_proj, bproj, x, x1, (unsigned short*)nullptr, M, 768, 768);

    ln_kernel<<<2048, 256, 0, stream>>>(x1, ln2g, ln2b, bufA);

    gemm_bt<2><<<dim3(3072 / 128, M / 128), 256, 0, stream>>>(
        bufA, wt_fc, bfc, (const float*)nullptr, (float*)nullptr, bufB, M, 3072, 768);

    gemm_bt<1><<<dim3(768 / 128, M / 128), 256, 0, stream>>>(
        bufB, wt_fc2, bfc2, x1, out, (unsigned short*)nullptr, M, 768, 3072);
}

// Round 4
// 468.526 us; speedup vs baseline: 1.0750x; 1.0478x over previous
//
#include <hip/hip_runtime.h>
#include <hip/hip_bf16.h>
#include <stdint.h>

#define DEV __device__ __forceinline__

typedef __attribute__((ext_vector_type(8))) short     short8;   // 8 x bf16 bits
typedef __attribute__((ext_vector_type(4))) float     f32x4;
typedef __attribute__((ext_vector_type(4))) unsigned short ushort4v;

DEV float bf2f(unsigned short u) { return __uint_as_float(((uint32_t)u) << 16); }
DEV unsigned short f2bf(float f) {
    uint32_t x = __float_as_uint(f);
    return (unsigned short)((x + 0x7FFFu + ((x >> 16) & 1u)) >> 16);  // RNE
}

DEV f32x4 mfma16(short8 a, short8 b, f32x4 c) {
    return __builtin_amdgcn_mfma_f32_16x16x32_bf16(a, b, c, 0, 0, 0);
}

#define AS1C const __attribute__((address_space(1)))
#define AS3  __attribute__((address_space(3)))

DEV void gload_lds16(const void* g, void* l) {
    __builtin_amdgcn_global_load_lds((AS1C void*)g, (AS3 void*)l, 16, 0, 0);
}

// ---------------------------------------------------------------- LayerNorm
__global__ __launch_bounds__(256) void ln_kernel(const float* __restrict__ x,
                                                 const float* __restrict__ g,
                                                 const float* __restrict__ b,
                                                 unsigned short* __restrict__ out)
{
    const int lane = threadIdx.x & 63;
    const int row  = blockIdx.x * 4 + (threadIdx.x >> 6);
    const float* xr = x + (size_t)row * 768;

    f32x4 v[3];
    float s = 0.f, sq = 0.f;
#pragma unroll
    for (int i = 0; i < 3; ++i) {
        v[i] = *(const f32x4*)(xr + i * 256 + lane * 4);
#pragma unroll
        for (int j = 0; j < 4; ++j) { s += v[i][j]; sq = fmaf(v[i][j], v[i][j], sq); }
    }
#pragma unroll
    for (int off = 32; off; off >>= 1) { s += __shfl_xor(s, off); sq += __shfl_xor(sq, off); }
    const float mean = s * (1.0f / 768.0f);
    const float rstd = rsqrtf(sq * (1.0f / 768.0f) - mean * mean + 1e-5f);

#pragma unroll
    for (int i = 0; i < 3; ++i) {
        f32x4 gg = *(const f32x4*)(g + i * 256 + lane * 4);
        f32x4 bb = *(const f32x4*)(b + i * 256 + lane * 4);
        ushort4v o;
#pragma unroll
        for (int j = 0; j < 4; ++j) o[j] = f2bf((v[i][j] - mean) * rstd * gg[j] + bb[j]);
        *(ushort4v*)(out + (size_t)row * 768 + i * 256 + lane * 4) = o;
    }
}

// ------------------------------------------- weight convert fp32[K][N] -> bf16[N][K]
__global__ __launch_bounds__(256) void wconv_kernel(const float* __restrict__ W,
                                                    unsigned short* __restrict__ Wt,
                                                    int K, int N)
{
    __shared__ float t[32][33];
    const int tx = threadIdx.x & 31, ty = threadIdx.x >> 5;
    const int n0 = blockIdx.x * 32, k0 = blockIdx.y * 32;
#pragma unroll
    for (int i = 0; i < 4; ++i)
        t[ty + i * 8][tx] = W[(size_t)(k0 + ty + i * 8) * N + n0 + tx];
    __syncthreads();
#pragma unroll
    for (int i = 0; i < 4; ++i)
        Wt[(size_t)(n0 + ty + i * 8) * K + k0 + tx] = f2bf(t[tx][ty + i * 8]);
}

// ---------------------------------------------------------------- GEMM (NT)
template <int EPI>
__global__ __launch_bounds__(256) void gemm_bt(const unsigned short* __restrict__ A,
                                               const unsigned short* __restrict__ Bt,
                                               const float* __restrict__ bias,
                                               const float* __restrict__ res,
                                               float* __restrict__ outf,
                                               unsigned short* __restrict__ outh,
                                               int M, int N, int K)
{
    __shared__ unsigned short As[128 * 32];
    __shared__ unsigned short Bs[128 * 32];
    const int tid = threadIdx.x;
    const int lane = tid & 63, wv = tid >> 6;
    const int r16 = lane & 15, g4 = lane >> 4;
    const int wm = wv >> 1, wn = wv & 1;
    const int n0 = blockIdx.x * 128, m0 = blockIdx.y * 128;

    f32x4 acc[4][4] = {};

    for (int k0 = 0; k0 < K; k0 += 32) {
#pragma unroll
        for (int i = 0; i < 2; ++i) {
            const int chunk0 = wv * 128 + i * 64;           // wave-uniform LDS base
            const int c = chunk0 + lane;                     // 16B chunk id
            const unsigned short* ga = A  + (size_t)(m0 + (c >> 2)) * K + k0 + (c & 3) * 8;
            const unsigned short* gb = Bt + (size_t)(n0 + (c >> 2)) * K + k0 + (c & 3) * 8;
            gload_lds16(ga, (char*)As + (size_t)chunk0 * 16);
            gload_lds16(gb, (char*)Bs + (size_t)chunk0 * 16);
        }
        __syncthreads();

        short8 af[4], bfr[4];
#pragma unroll
        for (int i = 0; i < 4; ++i)
            af[i] = *(const short8*)(As + (wm * 64 + i * 16 + r16) * 32 + g4 * 8);
#pragma unroll
        for (int j = 0; j < 4; ++j)
            bfr[j] = *(const short8*)(Bs + (wn * 64 + j * 16 + r16) * 32 + g4 * 8);
#pragma unroll
        for (int i = 0; i < 4; ++i)
#pragma unroll
            for (int j = 0; j < 4; ++j)
                acc[i][j] = mfma16(af[i], bfr[j], acc[i][j]);
        __syncthreads();
    }

#pragma unroll
    for (int i = 0; i < 4; ++i) {
#pragma unroll
        for (int j = 0; j < 4; ++j) {
            const int row = m0 + wm * 64 + i * 16 + g4 * 4;
            const int col = n0 + wn * 64 + j * 16 + r16;
            const float bv = bias[col];
#pragma unroll
            for (int r = 0; r < 4; ++r) {
                const float v = acc[i][j][r] + bv;
                const size_t idx = (size_t)(row + r) * N + col;
                if constexpr (EPI == 0) {
                    outh[idx] = f2bf(v);
                } else if constexpr (EPI == 1) {
                    outf[idx] = v + res[idx];
                } else {
                    const float ge = 0.5f * v * (1.0f + erff(v * 0.70710678118654752f));
                    outh[idx] = f2bf(ge);
                }
            }
        }
    }
}

// ---------------------------------------------------------------- attention
// 4 waves/block (32 q-rows each), KVBLK=64.
// K: gload_lds (linear dest) with XOR chunk swizzle on BOTH global source and
//    ds_read (rule 21), double-buffered, prefetched under compute.
// V: coalesced reg load (prefetched), transposed into swizzled Vt[d][k] via
//    conflict-free scalar ds_writes; PV B-fragments are plain short8 reads.
__global__ __launch_bounds__(256) void attn_kernel(const unsigned short* __restrict__ qkv,
                                                   unsigned short* __restrict__ out)
{
    __shared__ alignas(16) unsigned short K_lds[2][64][64];  // phys chunk k2 = logical k2 ^ (row&7)
    __shared__ alignas(16) unsigned short Vt[64][64];        // [d][k], phys chunk = (k>>3) ^ (d&7)
    __shared__ alignas(16) unsigned short P_lds[4][2][16][72];

    const int tid  = threadIdx.x;
    const int lane = tid & 63, w = tid >> 6;
    const int r16 = lane & 15, g4 = lane >> 4;
    const int qb = blockIdx.x, h = blockIdx.y, b = blockIdx.z;
    const int C3 = 2304, T = 1024;
    const int qt  = qb * 4 + w;          // this wave's q-tile (32 rows)
    const int gr0 = b * T + qt * 32;
    const int qc  = h * 64;
    const int ns  = 2 * qb + 2;          // 64-key steps for this block

    const unsigned short* kbase = qkv + (size_t)(b * T) * C3 + 768 + qc;
    const unsigned short* vbase = kbase + 768;

    // Q fragments, pre-scaled by 1/8 (exact in bf16)
    short8 qf[2][2];
#pragma unroll
    for (int mt = 0; mt < 2; ++mt)
#pragma unroll
        for (int ks = 0; ks < 2; ++ks) {
            short8 v = *(const short8*)(qkv + (size_t)(gr0 + mt * 16 + r16) * C3 + qc + ks * 32 + g4 * 8);
#pragma unroll
            for (int j = 0; j < 8; ++j)
                v[j] = (short)f2bf(bf2f((unsigned short)v[j]) * 0.125f);
            qf[mt][ks] = v;
        }

    auto STAGE_K = [&](int st, int buf) {
#pragma unroll
        for (int i = 0; i < 2; ++i) {
            const int cb = i * 256 + w * 64;   // wave-uniform chunk base
            const int c  = cb + lane;
            const int row = c >> 3, k2 = c & 7;
            gload_lds16(kbase + (size_t)(st * 64 + row) * C3 + (size_t)((k2 ^ (row & 7)) * 8),
                        (char*)K_lds[buf] + (size_t)cb * 16);
        }
    };

    f32x4 o[2][4] = {};
    float mst[2][4], lst[2][4];
#pragma unroll
    for (int mt = 0; mt < 2; ++mt)
#pragma unroll
        for (int r = 0; r < 4; ++r) { mst[mt][r] = -1e30f; lst[mt][r] = 0.f; }

    short8 vreg[2];
    STAGE_K(0, 0);
#pragma unroll
    for (int i = 0; i < 2; ++i)
        vreg[i] = *(const short8*)(vbase + (size_t)lane * C3 + w * 16 + i * 8);

    for (int s = 0; s < ns; ++s) {
        __syncthreads();   // bar1: K(s) landed (vmcnt drain); Vt(s-1) readers done
        // transpose V(s) into Vt (conflict-free swizzled scalar writes)
#pragma unroll
        for (int i = 0; i < 2; ++i)
#pragma unroll
            for (int j = 0; j < 8; ++j)
                Vt[w * 16 + i * 8 + j][(((lane >> 3) ^ j) << 3) | (lane & 7)] =
                    (unsigned short)vreg[i][j];
        __syncthreads();   // bar2: Vt(s) visible (nothing in flight -> cheap)

        if (s + 1 < ns) {  // prefetch next step; drains at next bar1, after compute
            STAGE_K(s + 1, (s + 1) & 1);
#pragma unroll
            for (int i = 0; i < 2; ++i)
                vreg[i] = *(const short8*)(vbase + (size_t)((s + 1) * 64 + lane) * C3 + w * 16 + i * 8);
        }

        if (s * 64 <= qt * 32 + 31) {
            const int buf = s & 1;
            // ---- QK^T (16 MFMA)
            short8 kf[4][2];
#pragma unroll
            for (int kt = 0; kt < 4; ++kt)
#pragma unroll
                for (int ks = 0; ks < 2; ++ks) {
                    const int row = kt * 16 + r16;
                    const int pc  = (ks * 4 + g4) ^ (row & 7);
                    kf[kt][ks] = *(const short8*)&K_lds[buf][row][pc * 8];
                }
            f32x4 sv[2][4] = {};
#pragma unroll
            for (int mt = 0; mt < 2; ++mt)
#pragma unroll
                for (int kt = 0; kt < 4; ++kt)
#pragma unroll
                    for (int ks = 0; ks < 2; ++ks)
                        sv[mt][kt] = mfma16(qf[mt][ks], kf[kt][ks], sv[mt][kt]);

            if (s * 64 + 63 > qt * 32) {   // causal mask (tile straddles diagonal)
#pragma unroll
                for (int mt = 0; mt < 2; ++mt)
#pragma unroll
                    for (int kt = 0; kt < 4; ++kt)
#pragma unroll
                        for (int r = 0; r < 4; ++r)
                            if (s * 64 + kt * 16 + r16 > qt * 32 + mt * 16 + g4 * 4 + r)
                                sv[mt][kt][r] = -1e30f;
            }

            // ---- online softmax (8 rows/lane handled across shuffle groups)
#pragma unroll
            for (int mt = 0; mt < 2; ++mt) {
#pragma unroll
                for (int r = 0; r < 4; ++r) {
                    float mx = fmaxf(fmaxf(sv[mt][0][r], sv[mt][1][r]),
                                     fmaxf(sv[mt][2][r], sv[mt][3][r]));
#pragma unroll
                    for (int off = 8; off; off >>= 1) mx = fmaxf(mx, __shfl_xor(mx, off));
                    const float mnew  = fmaxf(mst[mt][r], mx);
                    const float alpha = __expf(mst[mt][r] - mnew);
                    mst[mt][r] = mnew;
                    float p[4], rs = 0.f;
#pragma unroll
                    for (int kt = 0; kt < 4; ++kt) {
                        p[kt] = __expf(sv[mt][kt][r] - mnew);
                        rs += p[kt];
                    }
#pragma unroll
                    for (int off = 8; off; off >>= 1) rs += __shfl_xor(rs, off);
                    lst[mt][r] = lst[mt][r] * alpha + rs;
#pragma unroll
                    for (int kt = 0; kt < 4; ++kt)
                        P_lds[w][mt][g4 * 4 + r][kt * 16 + r16] = f2bf(p[kt]);
#pragma unroll
                    for (int n = 0; n < 4; ++n) o[mt][n][r] *= alpha;
                }
            }

            // ---- PV (plain short8 B-fragments from swizzled Vt)
            short8 pa[2][2];
#pragma unroll
            for (int mt = 0; mt < 2; ++mt)
#pragma unroll
                for (int h2 = 0; h2 < 2; ++h2)
                    pa[mt][h2] = *(const short8*)&P_lds[w][mt][r16][h2 * 32 + g4 * 8];
            short8 vf2[2][4];
#pragma unroll
            for (int h2 = 0; h2 < 2; ++h2)
#pragma unroll
                for (int n = 0; n < 4; ++n)
                    vf2[h2][n] = *(const short8*)&Vt[n * 16 + r16][((h2 * 4 + g4) ^ (r16 & 7)) << 3];
#pragma unroll
            for (int h2 = 0; h2 < 2; ++h2)
#pragma unroll
                for (int n = 0; n < 4; ++n) {
                    o[0][n] = mfma16(pa[0][h2], vf2[h2][n], o[0][n]);
                    o[1][n] = mfma16(pa[1][h2], vf2[h2][n], o[1][n]);
                }
        }
    }

#pragma unroll
    for (int mt = 0; mt < 2; ++mt)
#pragma unroll
        for (int n = 0; n < 4; ++n)
#pragma unroll
            for (int r = 0; r < 4; ++r)
                out[(size_t)(gr0 + mt * 16 + g4 * 4 + r) * 768 + qc + n * 16 + r16] =
                    f2bf(o[mt][n][r] / lst[mt][r]);
}

// ---------------------------------------------------------------- launcher
extern "C" void kernel_launch(void* const* d_in, const int* in_sizes, int n_in,
                              void* d_out, int out_size, void* d_ws, size_t ws_size,
                              hipStream_t stream)
{
    const float* x     = (const float*)d_in[0];
    const float* ln1g  = (const float*)d_in[1];
    const float* ln1b  = (const float*)d_in[2];
    const float* Wattn = (const float*)d_in[3];
    const float* battn = (const float*)d_in[4];
    const float* Wproj = (const float*)d_in[5];
    const float* bproj = (const float*)d_in[6];
    const float* ln2g  = (const float*)d_in[7];
    const float* ln2b  = (const float*)d_in[8];
    const float* Wfc   = (const float*)d_in[9];
    const float* bfc   = (const float*)d_in[10];
    const float* Wfc2  = (const float*)d_in[11];
    const float* bfc2  = (const float*)d_in[12];
    float* out = (float*)d_out;

    char* p = (char*)d_ws;
    auto alloc = [&](size_t bytes) { char* q = p; p += (bytes + 255) & ~(size_t)255; return q; };
    unsigned short* wt_attn = (unsigned short*)alloc(768ull * 2304 * 2);
    unsigned short* wt_proj = (unsigned short*)alloc(768ull * 768 * 2);
    unsigned short* wt_fc   = (unsigned short*)alloc(768ull * 3072 * 2);
    unsigned short* wt_fc2  = (unsigned short*)alloc(3072ull * 768 * 2);
    unsigned short* bufA    = (unsigned short*)alloc(8192ull * 768 * 2);   // xln1 -> attn_out -> hln2
    unsigned short* bufB    = (unsigned short*)alloc(8192ull * 3072 * 2);  // qkv -> h_act
    float*          x1      = (float*)alloc(8192ull * 768 * 4);            // x + attn residual

    const int M = 8192;

    wconv_kernel<<<dim3(2304 / 32, 768 / 32), 256, 0, stream>>>(Wattn, wt_attn, 768, 2304);
    wconv_kernel<<<dim3(768 / 32, 768 / 32), 256, 0, stream>>>(Wproj, wt_proj, 768, 768);
    wconv_kernel<<<dim3(3072 / 32, 768 / 32), 256, 0, stream>>>(Wfc, wt_fc, 768, 3072);
    wconv_kernel<<<dim3(768 / 32, 3072 / 32), 256, 0, stream>>>(Wfc2, wt_fc2, 3072, 768);

    ln_kernel<<<2048, 256, 0, stream>>>(x, ln1g, ln1b, bufA);

    gemm_bt<0><<<dim3(2304 / 128, M / 128), 256, 0, stream>>>(
        bufA, wt_attn, battn, (const float*)nullptr, (float*)nullptr, bufB, M, 2304, 768);

    attn_kernel<<<dim3(8, 12, 8), 256, 0, stream>>>(bufB, bufA);

    gemm_bt<1><<<dim3(768 / 128, M / 128), 256, 0, stream>>>(
        bufA, wt_proj, bproj, x, x1, (unsigned short*)nullptr, M, 768, 768);

    ln_kernel<<<2048, 256, 0, stream>>>(x1, ln2g, ln2b, bufA);

    gemm_bt<2><<<dim3(3072 / 128, M / 128), 256, 0, stream>>>(
        bufA, wt_fc, bfc, (const float*)nullptr, (float*)nullptr, bufB, M, 3072, 768);

    gemm_bt<1><<<dim3(768 / 128, M / 128), 256, 0, stream>>>(
        bufB, wt_fc2, bfc2, x1, out, (unsigned short*)nullptr, M, 768, 3072);
}

// Round 5
// 396.126 us; speedup vs baseline: 1.2714x; 1.1828x over previous
//
#include <hip/hip_runtime.h>
#include <hip/hip_bf16.h>
#include <stdint.h>

#define DEV __device__ __forceinline__

typedef __attribute__((ext_vector_type(8))) short     short8;   // 8 x bf16 bits
typedef __attribute__((ext_vector_type(4))) float     f32x4;
typedef __attribute__((ext_vector_type(4))) unsigned short ushort4v;

DEV float bf2f(unsigned short u) { return __uint_as_float(((uint32_t)u) << 16); }
DEV unsigned short f2bf(float f) {
    uint32_t x = __float_as_uint(f);
    return (unsigned short)((x + 0x7FFFu + ((x >> 16) & 1u)) >> 16);  // RNE
}

DEV f32x4 mfma16(short8 a, short8 b, f32x4 c) {
    return __builtin_amdgcn_mfma_f32_16x16x32_bf16(a, b, c, 0, 0, 0);
}

#define AS1C const __attribute__((address_space(1)))
#define AS3  __attribute__((address_space(3)))

DEV void gload_lds16(const void* g, void* l) {
    __builtin_amdgcn_global_load_lds((AS1C void*)g, (AS3 void*)l, 16, 0, 0);
}

// ---------------------------------------------------------------- LayerNorm
__global__ __launch_bounds__(256) void ln_kernel(const float* __restrict__ x,
                                                 const float* __restrict__ g,
                                                 const float* __restrict__ b,
                                                 unsigned short* __restrict__ out)
{
    const int lane = threadIdx.x & 63;
    const int row  = blockIdx.x * 4 + (threadIdx.x >> 6);
    const float* xr = x + (size_t)row * 768;

    f32x4 v[3];
    float s = 0.f, sq = 0.f;
#pragma unroll
    for (int i = 0; i < 3; ++i) {
        v[i] = *(const f32x4*)(xr + i * 256 + lane * 4);
#pragma unroll
        for (int j = 0; j < 4; ++j) { s += v[i][j]; sq = fmaf(v[i][j], v[i][j], sq); }
    }
#pragma unroll
    for (int off = 32; off; off >>= 1) { s += __shfl_xor(s, off); sq += __shfl_xor(sq, off); }
    const float mean = s * (1.0f / 768.0f);
    const float rstd = rsqrtf(sq * (1.0f / 768.0f) - mean * mean + 1e-5f);

#pragma unroll
    for (int i = 0; i < 3; ++i) {
        f32x4 gg = *(const f32x4*)(g + i * 256 + lane * 4);
        f32x4 bb = *(const f32x4*)(b + i * 256 + lane * 4);
        ushort4v o;
#pragma unroll
        for (int j = 0; j < 4; ++j) o[j] = f2bf((v[i][j] - mean) * rstd * gg[j] + bb[j]);
        *(ushort4v*)(out + (size_t)row * 768 + i * 256 + lane * 4) = o;
    }
}

// ------------------------------------------- weight convert fp32[K][N] -> bf16[N][K]
__global__ __launch_bounds__(256) void wconv_kernel(const float* __restrict__ W,
                                                    unsigned short* __restrict__ Wt,
                                                    int K, int N)
{
    __shared__ float t[32][33];
    const int tx = threadIdx.x & 31, ty = threadIdx.x >> 5;
    const int n0 = blockIdx.x * 32, k0 = blockIdx.y * 32;
#pragma unroll
    for (int i = 0; i < 4; ++i)
        t[ty + i * 8][tx] = W[(size_t)(k0 + ty + i * 8) * N + n0 + tx];
    __syncthreads();
#pragma unroll
    for (int i = 0; i < 4; ++i)
        Wt[(size_t)(n0 + ty + i * 8) * K + k0 + tx] = f2bf(t[tx][ty + i * 8]);
}

// ---------------------------------------------------------------- GEMM (NT) 128x128
template <int EPI>
__global__ __launch_bounds__(256) void gemm_bt(const unsigned short* __restrict__ A,
                                               const unsigned short* __restrict__ Bt,
                                               const float* __restrict__ bias,
                                               const float* __restrict__ res,
                                               float* __restrict__ outf,
                                               unsigned short* __restrict__ outh,
                                               int M, int N, int K)
{
    __shared__ unsigned short As[128 * 32];
    __shared__ unsigned short Bs[128 * 32];
    const int tid = threadIdx.x;
    const int lane = tid & 63, wv = tid >> 6;
    const int r16 = lane & 15, g4 = lane >> 4;
    const int wm = wv >> 1, wn = wv & 1;
    const int n0 = blockIdx.x * 128, m0 = blockIdx.y * 128;

    f32x4 acc[4][4] = {};

    for (int k0 = 0; k0 < K; k0 += 32) {
#pragma unroll
        for (int i = 0; i < 2; ++i) {
            const int chunk0 = wv * 128 + i * 64;           // wave-uniform LDS base
            const int c = chunk0 + lane;                     // 16B chunk id
            const unsigned short* ga = A  + (size_t)(m0 + (c >> 2)) * K + k0 + (c & 3) * 8;
            const unsigned short* gb = Bt + (size_t)(n0 + (c >> 2)) * K + k0 + (c & 3) * 8;
            gload_lds16(ga, (char*)As + (size_t)chunk0 * 16);
            gload_lds16(gb, (char*)Bs + (size_t)chunk0 * 16);
        }
        __syncthreads();

        short8 af[4], bfr[4];
#pragma unroll
        for (int i = 0; i < 4; ++i)
            af[i] = *(const short8*)(As + (wm * 64 + i * 16 + r16) * 32 + g4 * 8);
#pragma unroll
        for (int j = 0; j < 4; ++j)
            bfr[j] = *(const short8*)(Bs + (wn * 64 + j * 16 + r16) * 32 + g4 * 8);
#pragma unroll
        for (int i = 0; i < 4; ++i)
#pragma unroll
            for (int j = 0; j < 4; ++j)
                acc[i][j] = mfma16(af[i], bfr[j], acc[i][j]);
        __syncthreads();
    }

#pragma unroll
    for (int i = 0; i < 4; ++i) {
#pragma unroll
        for (int j = 0; j < 4; ++j) {
            const int row = m0 + wm * 64 + i * 16 + g4 * 4;
            const int col = n0 + wn * 64 + j * 16 + r16;
            const float bv = bias[col];
#pragma unroll
            for (int r = 0; r < 4; ++r) {
                const float v = acc[i][j][r] + bv;
                const size_t idx = (size_t)(row + r) * N + col;
                if constexpr (EPI == 0) {
                    outh[idx] = f2bf(v);
                } else if constexpr (EPI == 1) {
                    outf[idx] = v + res[idx];
                } else {
                    const float ge = 0.5f * v * (1.0f + erff(v * 0.70710678118654752f));
                    outh[idx] = f2bf(ge);
                }
            }
        }
    }
}

// ---------------------------------------------------------------- GEMM (NT) 64x128
// for N=768 GEMMs: grid (M/64, 6) = 768 blocks -> 3/CU, m-fastest keeps the
// n-panel L2-hot. EPI=1 epilogue only (f32 out = acc + bias + res).
__global__ __launch_bounds__(256) void gemm_bt64(const unsigned short* __restrict__ A,
                                                 const unsigned short* __restrict__ Bt,
                                                 const float* __restrict__ bias,
                                                 const float* __restrict__ res,
                                                 float* __restrict__ outf,
                                                 int M, int N, int K)
{
    __shared__ unsigned short As[64 * 32];
    __shared__ unsigned short Bs[128 * 32];
    const int tid = threadIdx.x;
    const int lane = tid & 63, wv = tid >> 6;
    const int r16 = lane & 15, g4 = lane >> 4;
    const int m0 = blockIdx.x * 64, n0 = blockIdx.y * 128;

    f32x4 acc[4][2] = {};

    for (int k0 = 0; k0 < K; k0 += 32) {
        const int cb = wv * 64;
        const int c  = cb + lane;
        // A: 256 chunks (64 rows x 4)
        gload_lds16(A + (size_t)(m0 + (c >> 2)) * K + k0 + (c & 3) * 8,
                    (char*)As + (size_t)cb * 16);
        // B: 512 chunks (128 rows x 4)
        gload_lds16(Bt + (size_t)(n0 + (c >> 2)) * K + k0 + (c & 3) * 8,
                    (char*)Bs + (size_t)cb * 16);
        gload_lds16(Bt + (size_t)(n0 + ((c + 256) >> 2)) * K + k0 + (c & 3) * 8,
                    (char*)Bs + (size_t)(cb + 256) * 16);
        __syncthreads();

        short8 af[4], bfr[2];
#pragma unroll
        for (int i = 0; i < 4; ++i)
            af[i] = *(const short8*)(As + (i * 16 + r16) * 32 + g4 * 8);
#pragma unroll
        for (int j = 0; j < 2; ++j)
            bfr[j] = *(const short8*)(Bs + (wv * 32 + j * 16 + r16) * 32 + g4 * 8);
#pragma unroll
        for (int i = 0; i < 4; ++i)
#pragma unroll
            for (int j = 0; j < 2; ++j)
                acc[i][j] = mfma16(af[i], bfr[j], acc[i][j]);
        __syncthreads();
    }

#pragma unroll
    for (int i = 0; i < 4; ++i) {
#pragma unroll
        for (int j = 0; j < 2; ++j) {
            const int row = m0 + i * 16 + g4 * 4;
            const int col = n0 + wv * 32 + j * 16 + r16;
            const float bv = bias[col];
#pragma unroll
            for (int r = 0; r < 4; ++r) {
                const size_t idx = (size_t)(row + r) * N + col;
                outf[idx] = acc[i][j][r] + bv + res[idx];
            }
        }
    }
}

// ---------------------------------------------------------------- attention
// 4 waves/block (32 q-rows each), KVBLK=64, ONE raw barrier per step.
// Grid: 1-D 768, LPT (heavy qb first) + same-XCD placement for shared (b,h).
// K: gload_lds, XOR chunk swizzle both sides, double-buffered.
// V: reg-staged (issued at step top, written at step end), swizzled Vt dbuf.
__global__ __launch_bounds__(256) void attn_kernel(const unsigned short* __restrict__ qkv,
                                                   unsigned short* __restrict__ out)
{
    __shared__ alignas(16) unsigned short K_lds[2][64][64];  // phys chunk = logical ^ (row&7)
    __shared__ alignas(16) unsigned short Vt[2][64][64];     // [d][k], phys chunk = (k>>3)^(d&7)
    __shared__ alignas(16) unsigned short P_lds[4][2][16][72];

    const int tid  = threadIdx.x;
    const int lane = tid & 63, w = tid >> 6;
    const int r16 = lane & 15, g4 = lane >> 4;
    const int bid = blockIdx.x;
    const int qb  = 7 - (bid / 96);      // LPT: heaviest first
    const int rem = bid % 96;            // 96 % 8 == 0 -> same (b,h) => same XCD
    const int h   = rem % 12;
    const int b   = rem / 12;
    const int C3 = 2304, T = 1024;
    const int qt  = qb * 4 + w;
    const int gr0 = b * T + qt * 32;
    const int qc  = h * 64;
    const int ns  = 2 * qb + 2;

    const unsigned short* kbase = qkv + (size_t)(b * T) * C3 + 768 + qc;
    const unsigned short* vbase = kbase + 768;

    // Q fragments, pre-scaled by 1/8 (exact in bf16)
    short8 qf[2][2];
#pragma unroll
    for (int mt = 0; mt < 2; ++mt)
#pragma unroll
        for (int ks = 0; ks < 2; ++ks) {
            short8 v = *(const short8*)(qkv + (size_t)(gr0 + mt * 16 + r16) * C3 + qc + ks * 32 + g4 * 8);
#pragma unroll
            for (int j = 0; j < 8; ++j)
                v[j] = (short)f2bf(bf2f((unsigned short)v[j]) * 0.125f);
            qf[mt][ks] = v;
        }

    auto STAGE_K = [&](int st, int buf) {
#pragma unroll
        for (int i = 0; i < 2; ++i) {
            const int cb = i * 256 + w * 64;   // wave-uniform chunk base
            const int c  = cb + lane;
            const int row = c >> 3, k2 = c & 7;
            gload_lds16(kbase + (size_t)(st * 64 + row) * C3 + (size_t)((k2 ^ (row & 7)) * 8),
                        (char*)K_lds[buf] + (size_t)cb * 16);
        }
    };
    auto WRITE_VT = [&](int buf, short8 v0, short8 v1) {
#pragma unroll
        for (int j = 0; j < 8; ++j) {
            Vt[buf][w * 16 + j]     [((((lane >> 3) ^ j) << 3) | (lane & 7))] = (unsigned short)v0[j];
            Vt[buf][w * 16 + 8 + j] [((((lane >> 3) ^ j) << 3) | (lane & 7))] = (unsigned short)v1[j];
        }
    };

    f32x4 o[2][4] = {};
    float mst[2][4], lst[2][4];
#pragma unroll
    for (int mt = 0; mt < 2; ++mt)
#pragma unroll
        for (int r = 0; r < 4; ++r) { mst[mt][r] = -1e30f; lst[mt][r] = 0.f; }

    // prologue: stage step 0, drain, publish Vt(0)
    STAGE_K(0, 0);
    {
        short8 v0 = *(const short8*)(vbase + (size_t)lane * C3 + w * 16);
        short8 v1 = *(const short8*)(vbase + (size_t)lane * C3 + w * 16 + 8);
        asm volatile("s_waitcnt vmcnt(0)" ::: "memory");
        WRITE_VT(0, v0, v1);
    }

    for (int s = 0; s < ns; ++s) {
        asm volatile("s_waitcnt lgkmcnt(0)" ::: "memory");  // Vt(s) writes committed
        asm volatile("s_barrier" ::: "memory");             // K(s)+Vt(s) visible to all
        __builtin_amdgcn_sched_barrier(0);

        short8 vb0, vb1;
        const bool more = (s + 1 < ns);
        if (more) {   // issue next-step staging; lands during compute
            STAGE_K(s + 1, (s + 1) & 1);
            vb0 = *(const short8*)(vbase + (size_t)((s + 1) * 64 + lane) * C3 + w * 16);
            vb1 = *(const short8*)(vbase + (size_t)((s + 1) * 64 + lane) * C3 + w * 16 + 8);
        }

        if (s * 64 <= qt * 32 + 31) {
            const int buf = s & 1;
            // ---- QK^T (16 MFMA)
            short8 kf[4][2];
#pragma unroll
            for (int kt = 0; kt < 4; ++kt)
#pragma unroll
                for (int ks = 0; ks < 2; ++ks) {
                    const int row = kt * 16 + r16;
                    const int pc  = (ks * 4 + g4) ^ (row & 7);
                    kf[kt][ks] = *(const short8*)&K_lds[buf][row][pc * 8];
                }
            f32x4 sv[2][4] = {};
#pragma unroll
            for (int mt = 0; mt < 2; ++mt)
#pragma unroll
                for (int kt = 0; kt < 4; ++kt)
#pragma unroll
                    for (int ks = 0; ks < 2; ++ks)
                        sv[mt][kt] = mfma16(qf[mt][ks], kf[kt][ks], sv[mt][kt]);

            if (s * 64 + 63 > qt * 32) {   // causal mask
#pragma unroll
                for (int mt = 0; mt < 2; ++mt)
#pragma unroll
                    for (int kt = 0; kt < 4; ++kt)
#pragma unroll
                        for (int r = 0; r < 4; ++r)
                            if (s * 64 + kt * 16 + r16 > qt * 32 + mt * 16 + g4 * 4 + r)
                                sv[mt][kt][r] = -1e30f;
            }

            // ---- online softmax
#pragma unroll
            for (int mt = 0; mt < 2; ++mt) {
#pragma unroll
                for (int r = 0; r < 4; ++r) {
                    float mx = fmaxf(fmaxf(sv[mt][0][r], sv[mt][1][r]),
                                     fmaxf(sv[mt][2][r], sv[mt][3][r]));
#pragma unroll
                    for (int off = 8; off; off >>= 1) mx = fmaxf(mx, __shfl_xor(mx, off));
                    const float mnew  = fmaxf(mst[mt][r], mx);
                    const float alpha = __expf(mst[mt][r] - mnew);
                    mst[mt][r] = mnew;
                    float p[4], rs = 0.f;
#pragma unroll
                    for (int kt = 0; kt < 4; ++kt) {
                        p[kt] = __expf(sv[mt][kt][r] - mnew);
                        rs += p[kt];
                    }
#pragma unroll
                    for (int off = 8; off; off >>= 1) rs += __shfl_xor(rs, off);
                    lst[mt][r] = lst[mt][r] * alpha + rs;
#pragma unroll
                    for (int kt = 0; kt < 4; ++kt)
                        P_lds[w][mt][g4 * 4 + r][kt * 16 + r16] = f2bf(p[kt]);
#pragma unroll
                    for (int n = 0; n < 4; ++n) o[mt][n][r] *= alpha;
                }
            }

            // ---- PV
            short8 pa[2][2];
#pragma unroll
            for (int mt = 0; mt < 2; ++mt)
#pragma unroll
                for (int h2 = 0; h2 < 2; ++h2)
                    pa[mt][h2] = *(const short8*)&P_lds[w][mt][r16][h2 * 32 + g4 * 8];
            short8 vf2[2][4];
#pragma unroll
            for (int h2 = 0; h2 < 2; ++h2)
#pragma unroll
                for (int n = 0; n < 4; ++n)
                    vf2[h2][n] = *(const short8*)&Vt[buf][n * 16 + r16][((h2 * 4 + g4) ^ (r16 & 7)) << 3];
#pragma unroll
            for (int h2 = 0; h2 < 2; ++h2)
#pragma unroll
                for (int n = 0; n < 4; ++n) {
                    o[0][n] = mfma16(pa[0][h2], vf2[h2][n], o[0][n]);
                    o[1][n] = mfma16(pa[1][h2], vf2[h2][n], o[1][n]);
                }
        }

        if (more) {   // publish Vt(s+1); K(s+1) transitively drained
            asm volatile("s_waitcnt vmcnt(0)" ::: "memory");
            WRITE_VT((s + 1) & 1, vb0, vb1);
        }
    }

#pragma unroll
    for (int mt = 0; mt < 2; ++mt)
#pragma unroll
        for (int n = 0; n < 4; ++n)
#pragma unroll
            for (int r = 0; r < 4; ++r)
                out[(size_t)(gr0 + mt * 16 + g4 * 4 + r) * 768 + qc + n * 16 + r16] =
                    f2bf(o[mt][n][r] / lst[mt][r]);
}

// ---------------------------------------------------------------- launcher
extern "C" void kernel_launch(void* const* d_in, const int* in_sizes, int n_in,
                              void* d_out, int out_size, void* d_ws, size_t ws_size,
                              hipStream_t stream)
{
    const float* x     = (const float*)d_in[0];
    const float* ln1g  = (const float*)d_in[1];
    const float* ln1b  = (const float*)d_in[2];
    const float* Wattn = (const float*)d_in[3];
    const float* battn = (const float*)d_in[4];
    const float* Wproj = (const float*)d_in[5];
    const float* bproj = (const float*)d_in[6];
    const float* ln2g  = (const float*)d_in[7];
    const float* ln2b  = (const float*)d_in[8];
    const float* Wfc   = (const float*)d_in[9];
    const float* bfc   = (const float*)d_in[10];
    const float* Wfc2  = (const float*)d_in[11];
    const float* bfc2  = (const float*)d_in[12];
    float* out = (float*)d_out;

    char* p = (char*)d_ws;
    auto alloc = [&](size_t bytes) { char* q = p; p += (bytes + 255) & ~(size_t)255; return q; };
    unsigned short* wt_attn = (unsigned short*)alloc(768ull * 2304 * 2);
    unsigned short* wt_proj = (unsigned short*)alloc(768ull * 768 * 2);
    unsigned short* wt_fc   = (unsigned short*)alloc(768ull * 3072 * 2);
    unsigned short* wt_fc2  = (unsigned short*)alloc(3072ull * 768 * 2);
    unsigned short* bufA    = (unsigned short*)alloc(8192ull * 768 * 2);   // xln1 -> attn_out -> hln2
    unsigned short* bufB    = (unsigned short*)alloc(8192ull * 3072 * 2);  // qkv -> h_act
    float*          x1      = (float*)alloc(8192ull * 768 * 4);            // x + attn residual

    const int M = 8192;

    wconv_kernel<<<dim3(2304 / 32, 768 / 32), 256, 0, stream>>>(Wattn, wt_attn, 768, 2304);
    wconv_kernel<<<dim3(768 / 32, 768 / 32), 256, 0, stream>>>(Wproj, wt_proj, 768, 768);
    wconv_kernel<<<dim3(3072 / 32, 768 / 32), 256, 0, stream>>>(Wfc, wt_fc, 768, 3072);
    wconv_kernel<<<dim3(768 / 32, 3072 / 32), 256, 0, stream>>>(Wfc2, wt_fc2, 3072, 768);

    ln_kernel<<<2048, 256, 0, stream>>>(x, ln1g, ln1b, bufA);

    gemm_bt<0><<<dim3(2304 / 128, M / 128), 256, 0, stream>>>(
        bufA, wt_attn, battn, (const float*)nullptr, (float*)nullptr, bufB, M, 2304, 768);

    attn_kernel<<<dim3(768), 256, 0, stream>>>(bufB, bufA);

    gemm_bt64<<<dim3(M / 64, 768 / 128), 256, 0, stream>>>(
        bufA, wt_proj, bproj, x, x1, M, 768, 768);

    ln_kernel<<<2048, 256, 0, stream>>>(x1, ln2g, ln2b, bufA);

    gemm_bt<2><<<dim3(3072 / 128, M / 128), 256, 0, stream>>>(
        bufA, wt_fc, bfc, (const float*)nullptr, (float*)nullptr, bufB, M, 3072, 768);

    gemm_bt64<<<dim3(M / 64, 768 / 128), 256, 0, stream>>>(
        bufB, wt_fc2, bfc2, x1, out, M, 768, 3072);
}

// Round 6
// 385.477 us; speedup vs baseline: 1.3066x; 1.0276x over previous
//
#include <hip/hip_runtime.h>
#include <hip/hip_bf16.h>
#include <stdint.h>

#define DEV __device__ __forceinline__

typedef __attribute__((ext_vector_type(8))) short     short8;   // 8 x bf16 bits
typedef __attribute__((ext_vector_type(4))) float     f32x4;
typedef __attribute__((ext_vector_type(4))) unsigned short ushort4v;

DEV float bf2f(unsigned short u) { return __uint_as_float(((uint32_t)u) << 16); }
DEV unsigned short f2bf(float f) {
    uint32_t x = __float_as_uint(f);
    return (unsigned short)((x + 0x7FFFu + ((x >> 16) & 1u)) >> 16);  // RNE
}

DEV f32x4 mfma16(short8 a, short8 b, f32x4 c) {
    return __builtin_amdgcn_mfma_f32_16x16x32_bf16(a, b, c, 0, 0, 0);
}

// tanh-form GELU via hw exp; |err| vs exact erf-gelu < 6e-4 (<< bf16 quantum)
DEV float gelu_f(float v) {
    const float u2 = 2.0f * v * (0.7978845608f + 0.0356774081f * v * v);
    const float e  = __expf(u2);
    const float th = 1.0f - 2.0f / (e + 1.0f);
    return 0.5f * v * (1.0f + th);
}

#define AS1C const __attribute__((address_space(1)))
#define AS3  __attribute__((address_space(3)))

DEV void gload_lds16(const void* g, void* l) {
    __builtin_amdgcn_global_load_lds((AS1C void*)g, (AS3 void*)l, 16, 0, 0);
}

// ---------------------------------------------------------------- LayerNorm
__global__ __launch_bounds__(256) void ln_kernel(const float* __restrict__ x,
                                                 const float* __restrict__ g,
                                                 const float* __restrict__ b,
                                                 unsigned short* __restrict__ out)
{
    const int lane = threadIdx.x & 63;
    const int row  = blockIdx.x * 4 + (threadIdx.x >> 6);
    const float* xr = x + (size_t)row * 768;

    f32x4 v[3];
    float s = 0.f, sq = 0.f;
#pragma unroll
    for (int i = 0; i < 3; ++i) {
        v[i] = *(const f32x4*)(xr + i * 256 + lane * 4);
#pragma unroll
        for (int j = 0; j < 4; ++j) { s += v[i][j]; sq = fmaf(v[i][j], v[i][j], sq); }
    }
#pragma unroll
    for (int off = 32; off; off >>= 1) { s += __shfl_xor(s, off); sq += __shfl_xor(sq, off); }
    const float mean = s * (1.0f / 768.0f);
    const float rstd = rsqrtf(sq * (1.0f / 768.0f) - mean * mean + 1e-5f);

#pragma unroll
    for (int i = 0; i < 3; ++i) {
        f32x4 gg = *(const f32x4*)(g + i * 256 + lane * 4);
        f32x4 bb = *(const f32x4*)(b + i * 256 + lane * 4);
        ushort4v o;
#pragma unroll
        for (int j = 0; j < 4; ++j) o[j] = f2bf((v[i][j] - mean) * rstd * gg[j] + bb[j]);
        *(ushort4v*)(out + (size_t)row * 768 + i * 256 + lane * 4) = o;
    }
}

// ------------------------------------------- weight convert fp32[K][N] -> bf16[N][K]
__global__ __launch_bounds__(256) void wconv_kernel(const float* __restrict__ W,
                                                    unsigned short* __restrict__ Wt,
                                                    int K, int N)
{
    __shared__ float t[32][33];
    const int tx = threadIdx.x & 31, ty = threadIdx.x >> 5;
    const int n0 = blockIdx.x * 32, k0 = blockIdx.y * 32;
#pragma unroll
    for (int i = 0; i < 4; ++i)
        t[ty + i * 8][tx] = W[(size_t)(k0 + ty + i * 8) * N + n0 + tx];
    __syncthreads();
#pragma unroll
    for (int i = 0; i < 4; ++i)
        Wt[(size_t)(n0 + ty + i * 8) * K + k0 + tx] = f2bf(t[tx][ty + i * 8]);
}

// ---------------------------------------------------------------- GEMM (NT) 128x128
// double-buffered LDS, prefetch-under-compute, ONE barrier per K-step.
template <int EPI>
__global__ __launch_bounds__(256) void gemm_bt(const unsigned short* __restrict__ A,
                                               const unsigned short* __restrict__ Bt,
                                               const float* __restrict__ bias,
                                               const float* __restrict__ res,
                                               float* __restrict__ outf,
                                               unsigned short* __restrict__ outh,
                                               int M, int N, int K)
{
    __shared__ unsigned short As[2][128 * 32];
    __shared__ unsigned short Bs[2][128 * 32];
    const int tid = threadIdx.x;
    const int lane = tid & 63, wv = tid >> 6;
    const int r16 = lane & 15, g4 = lane >> 4;
    const int wm = wv >> 1, wn = wv & 1;
    const int n0 = blockIdx.x * 128, m0 = blockIdx.y * 128;
    const int nt = K >> 5;

    auto STAGE = [&](int t, int buf) {
#pragma unroll
        for (int i = 0; i < 2; ++i) {
            const int chunk0 = wv * 128 + i * 64;           // wave-uniform LDS base
            const int c = chunk0 + lane;                     // 16B chunk id
            const unsigned short* ga = A  + (size_t)(m0 + (c >> 2)) * K + t * 32 + (c & 3) * 8;
            const unsigned short* gb = Bt + (size_t)(n0 + (c >> 2)) * K + t * 32 + (c & 3) * 8;
            gload_lds16(ga, (char*)As[buf] + (size_t)chunk0 * 16);
            gload_lds16(gb, (char*)Bs[buf] + (size_t)chunk0 * 16);
        }
    };

    f32x4 acc[4][4] = {};

    STAGE(0, 0);
    __syncthreads();

    for (int t = 0; t < nt; ++t) {
        const int buf = t & 1;
        if (t + 1 < nt) STAGE(t + 1, buf ^ 1);   // flies under this tile's compute

        short8 af[4], bfr[4];
#pragma unroll
        for (int i = 0; i < 4; ++i)
            af[i] = *(const short8*)(As[buf] + (wm * 64 + i * 16 + r16) * 32 + g4 * 8);
#pragma unroll
        for (int j = 0; j < 4; ++j)
            bfr[j] = *(const short8*)(Bs[buf] + (wn * 64 + j * 16 + r16) * 32 + g4 * 8);
#pragma unroll
        for (int i = 0; i < 4; ++i)
#pragma unroll
            for (int j = 0; j < 4; ++j)
                acc[i][j] = mfma16(af[i], bfr[j], acc[i][j]);
        __syncthreads();   // drains prefetch (vmcnt 0) + publishes; readers done
    }

#pragma unroll
    for (int i = 0; i < 4; ++i) {
#pragma unroll
        for (int j = 0; j < 4; ++j) {
            const int row = m0 + wm * 64 + i * 16 + g4 * 4;
            const int col = n0 + wn * 64 + j * 16 + r16;
            const float bv = bias[col];
#pragma unroll
            for (int r = 0; r < 4; ++r) {
                const float v = acc[i][j][r] + bv;
                const size_t idx = (size_t)(row + r) * N + col;
                if constexpr (EPI == 0) {
                    outh[idx] = f2bf(v);
                } else if constexpr (EPI == 1) {
                    outf[idx] = v + res[idx];
                } else {
                    outh[idx] = f2bf(gelu_f(v));
                }
            }
        }
    }
}

// ---------------------------------------------------------------- GEMM (NT) 64x128
// N=768 GEMMs: grid (M/64, 6) = 768 blocks -> 3/CU. Same prefetch pipeline.
__global__ __launch_bounds__(256) void gemm_bt64(const unsigned short* __restrict__ A,
                                                 const unsigned short* __restrict__ Bt,
                                                 const float* __restrict__ bias,
                                                 const float* __restrict__ res,
                                                 float* __restrict__ outf,
                                                 int M, int N, int K)
{
    __shared__ unsigned short As[2][64 * 32];
    __shared__ unsigned short Bs[2][128 * 32];
    const int tid = threadIdx.x;
    const int lane = tid & 63, wv = tid >> 6;
    const int r16 = lane & 15, g4 = lane >> 4;
    const int m0 = blockIdx.x * 64, n0 = blockIdx.y * 128;
    const int nt = K >> 5;

    auto STAGE = [&](int t, int buf) {
        const int cb = wv * 64;
        const int c  = cb + lane;
        gload_lds16(A + (size_t)(m0 + (c >> 2)) * K + t * 32 + (c & 3) * 8,
                    (char*)As[buf] + (size_t)cb * 16);
        gload_lds16(Bt + (size_t)(n0 + (c >> 2)) * K + t * 32 + (c & 3) * 8,
                    (char*)Bs[buf] + (size_t)cb * 16);
        gload_lds16(Bt + (size_t)(n0 + ((c + 256) >> 2)) * K + t * 32 + (c & 3) * 8,
                    (char*)Bs[buf] + (size_t)(cb + 256) * 16);
    };

    f32x4 acc[4][2] = {};

    STAGE(0, 0);
    __syncthreads();

    for (int t = 0; t < nt; ++t) {
        const int buf = t & 1;
        if (t + 1 < nt) STAGE(t + 1, buf ^ 1);

        short8 af[4], bfr[2];
#pragma unroll
        for (int i = 0; i < 4; ++i)
            af[i] = *(const short8*)(As[buf] + (i * 16 + r16) * 32 + g4 * 8);
#pragma unroll
        for (int j = 0; j < 2; ++j)
            bfr[j] = *(const short8*)(Bs[buf] + (wv * 32 + j * 16 + r16) * 32 + g4 * 8);
#pragma unroll
        for (int i = 0; i < 4; ++i)
#pragma unroll
            for (int j = 0; j < 2; ++j)
                acc[i][j] = mfma16(af[i], bfr[j], acc[i][j]);
        __syncthreads();
    }

#pragma unroll
    for (int i = 0; i < 4; ++i) {
#pragma unroll
        for (int j = 0; j < 2; ++j) {
            const int row = m0 + i * 16 + g4 * 4;
            const int col = n0 + wv * 32 + j * 16 + r16;
            const float bv = bias[col];
#pragma unroll
            for (int r = 0; r < 4; ++r) {
                const size_t idx = (size_t)(row + r) * N + col;
                outf[idx] = acc[i][j][r] + bv + res[idx];
            }
        }
    }
}

// ---------------------------------------------------------------- attention
// 4 waves/block (32 q-rows each), KVBLK=64, ONE raw barrier per step.
// Grid: 1-D 768, LPT (heavy qb first) + same-XCD placement for shared (b,h).
__global__ __launch_bounds__(256) void attn_kernel(const unsigned short* __restrict__ qkv,
                                                   unsigned short* __restrict__ out)
{
    __shared__ alignas(16) unsigned short K_lds[2][64][64];  // phys chunk = logical ^ (row&7)
    __shared__ alignas(16) unsigned short Vt[2][64][64];     // [d][k], phys chunk = (k>>3)^(d&7)
    __shared__ alignas(16) unsigned short P_lds[4][2][16][72];

    const int tid  = threadIdx.x;
    const int lane = tid & 63, w = tid >> 6;
    const int r16 = lane & 15, g4 = lane >> 4;
    const int bid = blockIdx.x;
    const int qb  = 7 - (bid / 96);      // LPT: heaviest first
    const int rem = bid % 96;            // 96 % 8 == 0 -> same (b,h) => same XCD
    const int h   = rem % 12;
    const int b   = rem / 12;
    const int C3 = 2304, T = 1024;
    const int qt  = qb * 4 + w;
    const int gr0 = b * T + qt * 32;
    const int qc  = h * 64;
    const int ns  = 2 * qb + 2;

    const unsigned short* kbase = qkv + (size_t)(b * T) * C3 + 768 + qc;
    const unsigned short* vbase = kbase + 768;

    // Q fragments, pre-scaled by 1/8 (exact in bf16)
    short8 qf[2][2];
#pragma unroll
    for (int mt = 0; mt < 2; ++mt)
#pragma unroll
        for (int ks = 0; ks < 2; ++ks) {
            short8 v = *(const short8*)(qkv + (size_t)(gr0 + mt * 16 + r16) * C3 + qc + ks * 32 + g4 * 8);
#pragma unroll
            for (int j = 0; j < 8; ++j)
                v[j] = (short)f2bf(bf2f((unsigned short)v[j]) * 0.125f);
            qf[mt][ks] = v;
        }

    auto STAGE_K = [&](int st, int buf) {
#pragma unroll
        for (int i = 0; i < 2; ++i) {
            const int cb = i * 256 + w * 64;   // wave-uniform chunk base
            const int c  = cb + lane;
            const int row = c >> 3, k2 = c & 7;
            gload_lds16(kbase + (size_t)(st * 64 + row) * C3 + (size_t)((k2 ^ (row & 7)) * 8),
                        (char*)K_lds[buf] + (size_t)cb * 16);
        }
    };
    auto WRITE_VT = [&](int buf, short8 v0, short8 v1) {
#pragma unroll
        for (int j = 0; j < 8; ++j) {
            Vt[buf][w * 16 + j]     [((((lane >> 3) ^ j) << 3) | (lane & 7))] = (unsigned short)v0[j];
            Vt[buf][w * 16 + 8 + j] [((((lane >> 3) ^ j) << 3) | (lane & 7))] = (unsigned short)v1[j];
        }
    };

    f32x4 o[2][4] = {};
    float mst[2][4], lst[2][4];
#pragma unroll
    for (int mt = 0; mt < 2; ++mt)
#pragma unroll
        for (int r = 0; r < 4; ++r) { mst[mt][r] = -1e30f; lst[mt][r] = 0.f; }

    // prologue: stage step 0, drain, publish Vt(0)
    STAGE_K(0, 0);
    {
        short8 v0 = *(const short8*)(vbase + (size_t)lane * C3 + w * 16);
        short8 v1 = *(const short8*)(vbase + (size_t)lane * C3 + w * 16 + 8);
        asm volatile("s_waitcnt vmcnt(0)" ::: "memory");
        WRITE_VT(0, v0, v1);
    }

    for (int s = 0; s < ns; ++s) {
        asm volatile("s_waitcnt lgkmcnt(0)" ::: "memory");  // Vt(s) writes committed
        asm volatile("s_barrier" ::: "memory");             // K(s)+Vt(s) visible to all
        __builtin_amdgcn_sched_barrier(0);

        short8 vb0, vb1;
        const bool more = (s + 1 < ns);
        if (more) {   // issue next-step staging; lands during compute
            STAGE_K(s + 1, (s + 1) & 1);
            vb0 = *(const short8*)(vbase + (size_t)((s + 1) * 64 + lane) * C3 + w * 16);
            vb1 = *(const short8*)(vbase + (size_t)((s + 1) * 64 + lane) * C3 + w * 16 + 8);
        }

        if (s * 64 <= qt * 32 + 31) {
            const int buf = s & 1;
            // ---- QK^T (16 MFMA)
            short8 kf[4][2];
#pragma unroll
            for (int kt = 0; kt < 4; ++kt)
#pragma unroll
                for (int ks = 0; ks < 2; ++ks) {
                    const int row = kt * 16 + r16;
                    const int pc  = (ks * 4 + g4) ^ (row & 7);
                    kf[kt][ks] = *(const short8*)&K_lds[buf][row][pc * 8];
                }
            f32x4 sv[2][4] = {};
#pragma unroll
            for (int mt = 0; mt < 2; ++mt)
#pragma unroll
                for (int kt = 0; kt < 4; ++kt)
#pragma unroll
                    for (int ks = 0; ks < 2; ++ks)
                        sv[mt][kt] = mfma16(qf[mt][ks], kf[kt][ks], sv[mt][kt]);

            if (s * 64 + 63 > qt * 32) {   // causal mask
#pragma unroll
                for (int mt = 0; mt < 2; ++mt)
#pragma unroll
                    for (int kt = 0; kt < 4; ++kt)
#pragma unroll
                        for (int r = 0; r < 4; ++r)
                            if (s * 64 + kt * 16 + r16 > qt * 32 + mt * 16 + g4 * 4 + r)
                                sv[mt][kt][r] = -1e30f;
            }

            // ---- online softmax
#pragma unroll
            for (int mt = 0; mt < 2; ++mt) {
#pragma unroll
                for (int r = 0; r < 4; ++r) {
                    float mx = fmaxf(fmaxf(sv[mt][0][r], sv[mt][1][r]),
                                     fmaxf(sv[mt][2][r], sv[mt][3][r]));
#pragma unroll
                    for (int off = 8; off; off >>= 1) mx = fmaxf(mx, __shfl_xor(mx, off));
                    const float mnew  = fmaxf(mst[mt][r], mx);
                    const float alpha = __expf(mst[mt][r] - mnew);
                    mst[mt][r] = mnew;
                    float p[4], rs = 0.f;
#pragma unroll
                    for (int kt = 0; kt < 4; ++kt) {
                        p[kt] = __expf(sv[mt][kt][r] - mnew);
                        rs += p[kt];
                    }
#pragma unroll
                    for (int off = 8; off; off >>= 1) rs += __shfl_xor(rs, off);
                    lst[mt][r] = lst[mt][r] * alpha + rs;
#pragma unroll
                    for (int kt = 0; kt < 4; ++kt)
                        P_lds[w][mt][g4 * 4 + r][kt * 16 + r16] = f2bf(p[kt]);
#pragma unroll
                    for (int n = 0; n < 4; ++n) o[mt][n][r] *= alpha;
                }
            }

            // ---- PV
            short8 pa[2][2];
#pragma unroll
            for (int mt = 0; mt < 2; ++mt)
#pragma unroll
                for (int h2 = 0; h2 < 2; ++h2)
                    pa[mt][h2] = *(const short8*)&P_lds[w][mt][r16][h2 * 32 + g4 * 8];
            short8 vf2[2][4];
#pragma unroll
            for (int h2 = 0; h2 < 2; ++h2)
#pragma unroll
                for (int n = 0; n < 4; ++n)
                    vf2[h2][n] = *(const short8*)&Vt[buf][n * 16 + r16][((h2 * 4 + g4) ^ (r16 & 7)) << 3];
#pragma unroll
            for (int h2 = 0; h2 < 2; ++h2)
#pragma unroll
                for (int n = 0; n < 4; ++n) {
                    o[0][n] = mfma16(pa[0][h2], vf2[h2][n], o[0][n]);
                    o[1][n] = mfma16(pa[1][h2], vf2[h2][n], o[1][n]);
                }
        }

        if (more) {   // publish Vt(s+1); K(s+1) transitively drained
            asm volatile("s_waitcnt vmcnt(0)" ::: "memory");
            WRITE_VT((s + 1) & 1, vb0, vb1);
        }
    }

#pragma unroll
    for (int mt = 0; mt < 2; ++mt)
#pragma unroll
        for (int n = 0; n < 4; ++n)
#pragma unroll
            for (int r = 0; r < 4; ++r)
                out[(size_t)(gr0 + mt * 16 + g4 * 4 + r) * 768 + qc + n * 16 + r16] =
                    f2bf(o[mt][n][r] / lst[mt][r]);
}

// ---------------------------------------------------------------- launcher
extern "C" void kernel_launch(void* const* d_in, const int* in_sizes, int n_in,
                              void* d_out, int out_size, void* d_ws, size_t ws_size,
                              hipStream_t stream)
{
    const float* x     = (const float*)d_in[0];
    const float* ln1g  = (const float*)d_in[1];
    const float* ln1b  = (const float*)d_in[2];
    const float* Wattn = (const float*)d_in[3];
    const float* battn = (const float*)d_in[4];
    const float* Wproj = (const float*)d_in[5];
    const float* bproj = (const float*)d_in[6];
    const float* ln2g  = (const float*)d_in[7];
    const float* ln2b  = (const float*)d_in[8];
    const float* Wfc   = (const float*)d_in[9];
    const float* bfc   = (const float*)d_in[10];
    const float* Wfc2  = (const float*)d_in[11];
    const float* bfc2  = (const float*)d_in[12];
    float* out = (float*)d_out;

    char* p = (char*)d_ws;
    auto alloc = [&](size_t bytes) { char* q = p; p += (bytes + 255) & ~(size_t)255; return q; };
    unsigned short* wt_attn = (unsigned short*)alloc(768ull * 2304 * 2);
    unsigned short* wt_proj = (unsigned short*)alloc(768ull * 768 * 2);
    unsigned short* wt_fc   = (unsigned short*)alloc(768ull * 3072 * 2);
    unsigned short* wt_fc2  = (unsigned short*)alloc(3072ull * 768 * 2);
    unsigned short* bufA    = (unsigned short*)alloc(8192ull * 768 * 2);   // xln1 -> attn_out -> hln2
    unsigned short* bufB    = (unsigned short*)alloc(8192ull * 3072 * 2);  // qkv -> h_act
    float*          x1      = (float*)alloc(8192ull * 768 * 4);            // x + attn residual

    const int M = 8192;

    wconv_kernel<<<dim3(2304 / 32, 768 / 32), 256, 0, stream>>>(Wattn, wt_attn, 768, 2304);
    wconv_kernel<<<dim3(768 / 32, 768 / 32), 256, 0, stream>>>(Wproj, wt_proj, 768, 768);
    wconv_kernel<<<dim3(3072 / 32, 768 / 32), 256, 0, stream>>>(Wfc, wt_fc, 768, 3072);
    wconv_kernel<<<dim3(768 / 32, 3072 / 32), 256, 0, stream>>>(Wfc2, wt_fc2, 3072, 768);

    ln_kernel<<<2048, 256, 0, stream>>>(x, ln1g, ln1b, bufA);

    gemm_bt<0><<<dim3(2304 / 128, M / 128), 256, 0, stream>>>(
        bufA, wt_attn, battn, (const float*)nullptr, (float*)nullptr, bufB, M, 2304, 768);

    attn_kernel<<<dim3(768), 256, 0, stream>>>(bufB, bufA);

    gemm_bt64<<<dim3(M / 64, 768 / 128), 256, 0, stream>>>(
        bufA, wt_proj, bproj, x, x1, M, 768, 768);

    ln_kernel<<<2048, 256, 0, stream>>>(x1, ln2g, ln2b, bufA);

    gemm_bt<2><<<dim3(3072 / 128, M / 128), 256, 0, stream>>>(
        bufA, wt_fc, bfc, (const float*)nullptr, (float*)nullptr, bufB, M, 3072, 768);

    gemm_bt64<<<dim3(M / 64, 768 / 128), 256, 0, stream>>>(
        bufB, wt_fc2, bfc2, x1, out, M, 768, 3072);
}

// Round 8
// 383.899 us; speedup vs baseline: 1.3119x; 1.0041x over previous
//
#include <hip/hip_runtime.h>
#include <hip/hip_bf16.h>
#include <stdint.h>

#define DEV __device__ __forceinline__

typedef __attribute__((ext_vector_type(8))) short     short8;   // 8 x bf16 bits
typedef __attribute__((ext_vector_type(4))) float     f32x4;
typedef __attribute__((ext_vector_type(4))) unsigned short ushort4v;

DEV float bf2f(unsigned short u) { return __uint_as_float(((uint32_t)u) << 16); }
DEV unsigned short f2bf(float f) {
    uint32_t x = __float_as_uint(f);
    return (unsigned short)((x + 0x7FFFu + ((x >> 16) & 1u)) >> 16);  // RNE
}

DEV f32x4 mfma16(short8 a, short8 b, f32x4 c) {
    return __builtin_amdgcn_mfma_f32_16x16x32_bf16(a, b, c, 0, 0, 0);
}

// tanh-form GELU via hw exp; |err| vs exact erf-gelu < 6e-4 (<< bf16 quantum)
DEV float gelu_f(float v) {
    const float u2 = 2.0f * v * (0.7978845608f + 0.0356774081f * v * v);
    const float e  = __expf(u2);
    const float th = 1.0f - 2.0f / (e + 1.0f);
    return 0.5f * v * (1.0f + th);
}

#define AS1C const __attribute__((address_space(1)))
#define AS3  __attribute__((address_space(3)))

DEV void gload_lds16(const void* g, void* l) {
    __builtin_amdgcn_global_load_lds((AS1C void*)g, (AS3 void*)l, 16, 0, 0);
}

// ---------------------------------------------------------------- LayerNorm
__global__ __launch_bounds__(256) void ln_kernel(const float* __restrict__ x,
                                                 const float* __restrict__ g,
                                                 const float* __restrict__ b,
                                                 unsigned short* __restrict__ out)
{
    const int lane = threadIdx.x & 63;
    const int row  = blockIdx.x * 4 + (threadIdx.x >> 6);
    const float* xr = x + (size_t)row * 768;

    f32x4 v[3];
    float s = 0.f, sq = 0.f;
#pragma unroll
    for (int i = 0; i < 3; ++i) {
        v[i] = *(const f32x4*)(xr + i * 256 + lane * 4);
#pragma unroll
        for (int j = 0; j < 4; ++j) { s += v[i][j]; sq = fmaf(v[i][j], v[i][j], sq); }
    }
#pragma unroll
    for (int off = 32; off; off >>= 1) { s += __shfl_xor(s, off); sq += __shfl_xor(sq, off); }
    const float mean = s * (1.0f / 768.0f);
    const float rstd = rsqrtf(sq * (1.0f / 768.0f) - mean * mean + 1e-5f);

#pragma unroll
    for (int i = 0; i < 3; ++i) {
        f32x4 gg = *(const f32x4*)(g + i * 256 + lane * 4);
        f32x4 bb = *(const f32x4*)(b + i * 256 + lane * 4);
        ushort4v o;
#pragma unroll
        for (int j = 0; j < 4; ++j) o[j] = f2bf((v[i][j] - mean) * rstd * gg[j] + bb[j]);
        *(ushort4v*)(out + (size_t)row * 768 + i * 256 + lane * 4) = o;
    }
}

// ------------------------------------------- weight convert fp32[K][N] -> bf16[N][K]
__global__ __launch_bounds__(256) void wconv_kernel(const float* __restrict__ W,
                                                    unsigned short* __restrict__ Wt,
                                                    int K, int N)
{
    __shared__ float t[32][33];
    const int tx = threadIdx.x & 31, ty = threadIdx.x >> 5;
    const int n0 = blockIdx.x * 32, k0 = blockIdx.y * 32;
#pragma unroll
    for (int i = 0; i < 4; ++i)
        t[ty + i * 8][tx] = W[(size_t)(k0 + ty + i * 8) * N + n0 + tx];
    __syncthreads();
#pragma unroll
    for (int i = 0; i < 4; ++i)
        Wt[(size_t)(n0 + ty + i * 8) * K + k0 + tx] = f2bf(t[tx][ty + i * 8]);
}

// ---------------------------------------------------------------- GEMM (NT) 128x128
// 3-deep LDS pipeline, raw s_barrier + counted vmcnt (never drain in loop).
template <int EPI>
__global__ __launch_bounds__(256) void gemm_bt(const unsigned short* __restrict__ A,
                                               const unsigned short* __restrict__ Bt,
                                               const float* __restrict__ bias,
                                               const float* __restrict__ res,
                                               float* __restrict__ outf,
                                               unsigned short* __restrict__ outh,
                                               int M, int N, int K)
{
    __shared__ unsigned short As[3][128 * 32];
    __shared__ unsigned short Bs[3][128 * 32];
    const int tid = threadIdx.x;
    const int lane = tid & 63, wv = tid >> 6;
    const int r16 = lane & 15, g4 = lane >> 4;
    const int wm = wv >> 1, wn = wv & 1;
    const int n0 = blockIdx.x * 128, m0 = blockIdx.y * 128;
    const int nt = K >> 5;

    auto STAGE = [&](int t, int buf) {   // 4 gload_lds / thread
#pragma unroll
        for (int i = 0; i < 2; ++i) {
            const int chunk0 = wv * 128 + i * 64;           // wave-uniform LDS base
            const int c = chunk0 + lane;                     // 16B chunk id
            const unsigned short* ga = A  + (size_t)(m0 + (c >> 2)) * K + t * 32 + (c & 3) * 8;
            const unsigned short* gb = Bt + (size_t)(n0 + (c >> 2)) * K + t * 32 + (c & 3) * 8;
            gload_lds16(ga, (char*)As[buf] + (size_t)chunk0 * 16);
            gload_lds16(gb, (char*)Bs[buf] + (size_t)chunk0 * 16);
        }
    };

    f32x4 acc[4][4] = {};

    STAGE(0, 0);
    STAGE(1, 1);

    for (int t = 0; t < nt; ++t) {
        // wait for MY stage(t) only; stage(t+1) stays in flight
        if (t + 1 < nt) { asm volatile("s_waitcnt vmcnt(4)" ::: "memory"); }
        else            { asm volatile("s_waitcnt vmcnt(0)" ::: "memory"); }
        __builtin_amdgcn_s_barrier();          // all waves: stage(t) ready, compute(t-1) done
        __builtin_amdgcn_sched_barrier(0);
        if (t + 2 < nt) STAGE(t + 2, (t + 2) % 3);   // overwrites buf of t-1 (safe)
        __builtin_amdgcn_sched_barrier(0);

        const int buf = t % 3;
        short8 af[4], bfr[4];
#pragma unroll
        for (int i = 0; i < 4; ++i)
            af[i] = *(const short8*)(As[buf] + (wm * 64 + i * 16 + r16) * 32 + g4 * 8);
#pragma unroll
        for (int j = 0; j < 4; ++j)
            bfr[j] = *(const short8*)(Bs[buf] + (wn * 64 + j * 16 + r16) * 32 + g4 * 8);
#pragma unroll
        for (int i = 0; i < 4; ++i)
#pragma unroll
            for (int j = 0; j < 4; ++j)
                acc[i][j] = mfma16(af[i], bfr[j], acc[i][j]);
    }

#pragma unroll
    for (int i = 0; i < 4; ++i) {
#pragma unroll
        for (int j = 0; j < 4; ++j) {
            const int row = m0 + wm * 64 + i * 16 + g4 * 4;
            const int col = n0 + wn * 64 + j * 16 + r16;
            const float bv = bias[col];
#pragma unroll
            for (int r = 0; r < 4; ++r) {
                const float v = acc[i][j][r] + bv;
                const size_t idx = (size_t)(row + r) * N + col;
                if constexpr (EPI == 0) {
                    outh[idx] = f2bf(v);
                } else if constexpr (EPI == 1) {
                    outf[idx] = v + res[idx];
                } else {
                    outh[idx] = f2bf(gelu_f(v));
                }
            }
        }
    }
}

// ---------------------------------------------------------------- GEMM (NT) 64x128
// N=768 GEMMs: grid (M/64, 6) = 768 blocks -> 3/CU. 4-deep pipeline.
__global__ __launch_bounds__(256) void gemm_bt64(const unsigned short* __restrict__ A,
                                                 const unsigned short* __restrict__ Bt,
                                                 const float* __restrict__ bias,
                                                 const float* __restrict__ res,
                                                 float* __restrict__ outf,
                                                 int M, int N, int K)
{
    __shared__ unsigned short As[4][64 * 32];
    __shared__ unsigned short Bs[4][128 * 32];
    const int tid = threadIdx.x;
    const int lane = tid & 63, wv = tid >> 6;
    const int r16 = lane & 15, g4 = lane >> 4;
    const int m0 = blockIdx.x * 64, n0 = blockIdx.y * 128;
    const int nt = K >> 5;

    auto STAGE = [&](int t, int buf) {   // 3 gload_lds / thread
        const int cb = wv * 64;
        const int c  = cb + lane;
        gload_lds16(A + (size_t)(m0 + (c >> 2)) * K + t * 32 + (c & 3) * 8,
                    (char*)As[buf] + (size_t)cb * 16);
        gload_lds16(Bt + (size_t)(n0 + (c >> 2)) * K + t * 32 + (c & 3) * 8,
                    (char*)Bs[buf] + (size_t)cb * 16);
        gload_lds16(Bt + (size_t)(n0 + ((c + 256) >> 2)) * K + t * 32 + (c & 3) * 8,
                    (char*)Bs[buf] + (size_t)(cb + 256) * 16);
    };

    f32x4 acc[4][2] = {};

    STAGE(0, 0);
    STAGE(1, 1);
    STAGE(2, 2);

    for (int t = 0; t < nt; ++t) {
        if (t + 2 < nt)      { asm volatile("s_waitcnt vmcnt(6)" ::: "memory"); }
        else if (t + 1 < nt) { asm volatile("s_waitcnt vmcnt(3)" ::: "memory"); }
        else                 { asm volatile("s_waitcnt vmcnt(0)" ::: "memory"); }
        __builtin_amdgcn_s_barrier();
        __builtin_amdgcn_sched_barrier(0);
        if (t + 3 < nt) STAGE(t + 3, (t + 3) & 3);
        __builtin_amdgcn_sched_barrier(0);

        const int buf = t & 3;
        short8 af[4], bfr[2];
#pragma unroll
        for (int i = 0; i < 4; ++i)
            af[i] = *(const short8*)(As[buf] + (i * 16 + r16) * 32 + g4 * 8);
#pragma unroll
        for (int j = 0; j < 2; ++j)
            bfr[j] = *(const short8*)(Bs[buf] + (wv * 32 + j * 16 + r16) * 32 + g4 * 8);
#pragma unroll
        for (int i = 0; i < 4; ++i)
#pragma unroll
            for (int j = 0; j < 2; ++j)
                acc[i][j] = mfma16(af[i], bfr[j], acc[i][j]);
    }

#pragma unroll
    for (int i = 0; i < 4; ++i) {
#pragma unroll
        for (int j = 0; j < 2; ++j) {
            const int row = m0 + i * 16 + g4 * 4;
            const int col = n0 + wv * 32 + j * 16 + r16;
            const float bv = bias[col];
#pragma unroll
            for (int r = 0; r < 4; ++r) {
                const size_t idx = (size_t)(row + r) * N + col;
                outf[idx] = acc[i][j][r] + bv + res[idx];
            }
        }
    }
}

// ---------------------------------------------------------------- attention
// 4 waves/block (32 q-rows each), KVBLK=64, ONE raw barrier per step.
// Grid: 1-D 768, LPT (heavy qb first) + same-XCD placement for shared (b,h).
__global__ __launch_bounds__(256) void attn_kernel(const unsigned short* __restrict__ qkv,
                                                   unsigned short* __restrict__ out)
{
    __shared__ alignas(16) unsigned short K_lds[2][64][64];  // phys chunk = logical ^ (row&7)
    __shared__ alignas(16) unsigned short Vt[2][64][64];     // [d][k], phys chunk = (k>>3)^(d&7)
    __shared__ alignas(16) unsigned short P_lds[4][2][16][72];

    const int tid  = threadIdx.x;
    const int lane = tid & 63, w = tid >> 6;
    const int r16 = lane & 15, g4 = lane >> 4;
    const int bid = blockIdx.x;
    const int qb  = 7 - (bid / 96);      // LPT: heaviest first
    const int rem = bid % 96;            // 96 % 8 == 0 -> same (b,h) => same XCD
    const int h   = rem % 12;
    const int b   = rem / 12;
    const int C3 = 2304, T = 1024;
    const int qt  = qb * 4 + w;
    const int gr0 = b * T + qt * 32;
    const int qc  = h * 64;
    const int ns  = 2 * qb + 2;

    const unsigned short* kbase = qkv + (size_t)(b * T) * C3 + 768 + qc;
    const unsigned short* vbase = kbase + 768;

    // Q fragments, pre-scaled by 1/8 (exact in bf16)
    short8 qf[2][2];
#pragma unroll
    for (int mt = 0; mt < 2; ++mt)
#pragma unroll
        for (int ks = 0; ks < 2; ++ks) {
            short8 v = *(const short8*)(qkv + (size_t)(gr0 + mt * 16 + r16) * C3 + qc + ks * 32 + g4 * 8);
#pragma unroll
            for (int j = 0; j < 8; ++j)
                v[j] = (short)f2bf(bf2f((unsigned short)v[j]) * 0.125f);
            qf[mt][ks] = v;
        }

    auto STAGE_K = [&](int st, int buf) {
#pragma unroll
        for (int i = 0; i < 2; ++i) {
            const int cb = i * 256 + w * 64;   // wave-uniform chunk base
            const int c  = cb + lane;
            const int row = c >> 3, k2 = c & 7;
            gload_lds16(kbase + (size_t)(st * 64 + row) * C3 + (size_t)((k2 ^ (row & 7)) * 8),
                        (char*)K_lds[buf] + (size_t)cb * 16);
        }
    };
    auto WRITE_VT = [&](int buf, short8 v0, short8 v1) {
#pragma unroll
        for (int j = 0; j < 8; ++j) {
            Vt[buf][w * 16 + j]     [((((lane >> 3) ^ j) << 3) | (lane & 7))] = (unsigned short)v0[j];
            Vt[buf][w * 16 + 8 + j] [((((lane >> 3) ^ j) << 3) | (lane & 7))] = (unsigned short)v1[j];
        }
    };

    f32x4 o[2][4] = {};
    float mst[2][4], lst[2][4];
#pragma unroll
    for (int mt = 0; mt < 2; ++mt)
#pragma unroll
        for (int r = 0; r < 4; ++r) { mst[mt][r] = -1e30f; lst[mt][r] = 0.f; }

    // prologue: stage step 0, drain, publish Vt(0)
    STAGE_K(0, 0);
    {
        short8 v0 = *(const short8*)(vbase + (size_t)lane * C3 + w * 16);
        short8 v1 = *(const short8*)(vbase + (size_t)lane * C3 + w * 16 + 8);
        asm volatile("s_waitcnt vmcnt(0)" ::: "memory");
        WRITE_VT(0, v0, v1);
    }

    for (int s = 0; s < ns; ++s) {
        asm volatile("s_waitcnt lgkmcnt(0)" ::: "memory");  // Vt(s) writes committed
        asm volatile("s_barrier" ::: "memory");             // K(s)+Vt(s) visible to all
        __builtin_amdgcn_sched_barrier(0);

        short8 vb0, vb1;
        const bool more = (s + 1 < ns);
        if (more) {   // issue next-step staging; lands during compute
            STAGE_K(s + 1, (s + 1) & 1);
            vb0 = *(const short8*)(vbase + (size_t)((s + 1) * 64 + lane) * C3 + w * 16);
            vb1 = *(const short8*)(vbase + (size_t)((s + 1) * 64 + lane) * C3 + w * 16 + 8);
        }

        if (s * 64 <= qt * 32 + 31) {
            const int buf = s & 1;
            // ---- QK^T (16 MFMA)
            short8 kf[4][2];
#pragma unroll
            for (int kt = 0; kt < 4; ++kt)
#pragma unroll
                for (int ks = 0; ks < 2; ++ks) {
                    const int row = kt * 16 + r16;
                    const int pc  = (ks * 4 + g4) ^ (row & 7);
                    kf[kt][ks] = *(const short8*)&K_lds[buf][row][pc * 8];
                }
            f32x4 sv[2][4] = {};
#pragma unroll
            for (int mt = 0; mt < 2; ++mt)
#pragma unroll
                for (int kt = 0; kt < 4; ++kt)
#pragma unroll
                    for (int ks = 0; ks < 2; ++ks)
                        sv[mt][kt] = mfma16(qf[mt][ks], kf[kt][ks], sv[mt][kt]);

            if (s * 64 + 63 > qt * 32) {   // causal mask
#pragma unroll
                for (int mt = 0; mt < 2; ++mt)
#pragma unroll
                    for (int kt = 0; kt < 4; ++kt)
#pragma unroll
                        for (int r = 0; r < 4; ++r)
                            if (s * 64 + kt * 16 + r16 > qt * 32 + mt * 16 + g4 * 4 + r)
                                sv[mt][kt][r] = -1e30f;
            }

            // ---- online softmax
#pragma unroll
            for (int mt = 0; mt < 2; ++mt) {
#pragma unroll
                for (int r = 0; r < 4; ++r) {
                    float mx = fmaxf(fmaxf(sv[mt][0][r], sv[mt][1][r]),
                                     fmaxf(sv[mt][2][r], sv[mt][3][r]));
#pragma unroll
                    for (int off = 8; off; off >>= 1) mx = fmaxf(mx, __shfl_xor(mx, off));
                    const float mnew  = fmaxf(mst[mt][r], mx);
                    const float alpha = __expf(mst[mt][r] - mnew);
                    mst[mt][r] = mnew;
                    float p[4], rs = 0.f;
#pragma unroll
                    for (int kt = 0; kt < 4; ++kt) {
                        p[kt] = __expf(sv[mt][kt][r] - mnew);
                        rs += p[kt];
                    }
#pragma unroll
                    for (int off = 8; off; off >>= 1) rs += __shfl_xor(rs, off);
                    lst[mt][r] = lst[mt][r] * alpha + rs;
#pragma unroll
                    for (int kt = 0; kt < 4; ++kt)
                        P_lds[w][mt][g4 * 4 + r][kt * 16 + r16] = f2bf(p[kt]);
#pragma unroll
                    for (int n = 0; n < 4; ++n) o[mt][n][r] *= alpha;
                }
            }

            // ---- PV
            short8 pa[2][2];
#pragma unroll
            for (int mt = 0; mt < 2; ++mt)
#pragma unroll
                for (int h2 = 0; h2 < 2; ++h2)
                    pa[mt][h2] = *(const short8*)&P_lds[w][mt][r16][h2 * 32 + g4 * 8];
            short8 vf2[2][4];
#pragma unroll
            for (int h2 = 0; h2 < 2; ++h2)
#pragma unroll
                for (int n = 0; n < 4; ++n)
                    vf2[h2][n] = *(const short8*)&Vt[buf][n * 16 + r16][((h2 * 4 + g4) ^ (r16 & 7)) << 3];
#pragma unroll
            for (int h2 = 0; h2 < 2; ++h2)
#pragma unroll
                for (int n = 0; n < 4; ++n) {
                    o[0][n] = mfma16(pa[0][h2], vf2[h2][n], o[0][n]);
                    o[1][n] = mfma16(pa[1][h2], vf2[h2][n], o[1][n]);
                }
        }

        if (more) {   // publish Vt(s+1); K(s+1) transitively drained
            asm volatile("s_waitcnt vmcnt(0)" ::: "memory");
            WRITE_VT((s + 1) & 1, vb0, vb1);
        }
    }

#pragma unroll
    for (int mt = 0; mt < 2; ++mt)
#pragma unroll
        for (int n = 0; n < 4; ++n)
#pragma unroll
            for (int r = 0; r < 4; ++r)
                out[(size_t)(gr0 + mt * 16 + g4 * 4 + r) * 768 + qc + n * 16 + r16] =
                    f2bf(o[mt][n][r] / lst[mt][r]);
}

// ---------------------------------------------------------------- launcher
extern "C" void kernel_launch(void* const* d_in, const int* in_sizes, int n_in,
                              void* d_out, int out_size, void* d_ws, size_t ws_size,
                              hipStream_t stream)
{
    const float* x     = (const float*)d_in[0];
    const float* ln1g  = (const float*)d_in[1];
    const float* ln1b  = (const float*)d_in[2];
    const float* Wattn = (const float*)d_in[3];
    const float* battn = (const float*)d_in[4];
    const float* Wproj = (const float*)d_in[5];
    const float* bproj = (const float*)d_in[6];
    const float* ln2g  = (const float*)d_in[7];
    const float* ln2b  = (const float*)d_in[8];
    const float* Wfc   = (const float*)d_in[9];
    const float* bfc   = (const float*)d_in[10];
    const float* Wfc2  = (const float*)d_in[11];
    const float* bfc2  = (const float*)d_in[12];
    float* out = (float*)d_out;

    char* p = (char*)d_ws;
    auto alloc = [&](size_t bytes) { char* q = p; p += (bytes + 255) & ~(size_t)255; return q; };
    unsigned short* wt_attn = (unsigned short*)alloc(768ull * 2304 * 2);
    unsigned short* wt_proj = (unsigned short*)alloc(768ull * 768 * 2);
    unsigned short* wt_fc   = (unsigned short*)alloc(768ull * 3072 * 2);
    unsigned short* wt_fc2  = (unsigned short*)alloc(3072ull * 768 * 2);
    unsigned short* bufA    = (unsigned short*)alloc(8192ull * 768 * 2);   // xln1 -> attn_out -> hln2
    unsigned short* bufB    = (unsigned short*)alloc(8192ull * 3072 * 2);  // qkv -> h_act
    float*          x1      = (float*)alloc(8192ull * 768 * 4);            // x + attn residual

    const int M = 8192;

    wconv_kernel<<<dim3(2304 / 32, 768 / 32), 256, 0, stream>>>(Wattn, wt_attn, 768, 2304);
    wconv_kernel<<<dim3(768 / 32, 768 / 32), 256, 0, stream>>>(Wproj, wt_proj, 768, 768);
    wconv_kernel<<<dim3(3072 / 32, 768 / 32), 256, 0, stream>>>(Wfc, wt_fc, 768, 3072);
    wconv_kernel<<<dim3(768 / 32, 3072 / 32), 256, 0, stream>>>(Wfc2, wt_fc2, 3072, 768);

    ln_kernel<<<2048, 256, 0, stream>>>(x, ln1g, ln1b, bufA);

    gemm_bt<0><<<dim3(2304 / 128, M / 128), 256, 0, stream>>>(
        bufA, wt_attn, battn, (const float*)nullptr, (float*)nullptr, bufB, M, 2304, 768);

    attn_kernel<<<dim3(768), 256, 0, stream>>>(bufB, bufA);

    gemm_bt64<<<dim3(M / 64, 768 / 128), 256, 0, stream>>>(
        bufA, wt_proj, bproj, x, x1, M, 768, 768);

    ln_kernel<<<2048, 256, 0, stream>>>(x1, ln2g, ln2b, bufA);

    gemm_bt<2><<<dim3(3072 / 128, M / 128), 256, 0, stream>>>(
        bufA, wt_fc, bfc, (const float*)nullptr, (float*)nullptr, bufB, M, 3072, 768);

    gemm_bt64<<<dim3(M / 64, 768 / 128), 256, 0, stream>>>(
        bufB, wt_fc2, bfc2, x1, out, M, 768, 3072);
}